// Round 1
// baseline (971.164 us; speedup 1.0000x reference)
//
#include <hip/hip_runtime.h>

// LinearAttentionCell: chunked linear attention, fp32 correctness-first version.
// y[b,t,:] = (phiQ_t . M_t) / (phiQ_t . z_t + 1e-5),
//   M_t = sum_{t'<=t} phiK_{t'} v_{t'}^T,  z_t = sum_{t'<=t} phiK_{t'}
// Chunked (T=128):
//   intra = tril(PQ_c PK_c^T) @ V_c          (k_gram + k_av, fully parallel)
//   inter = PQ_c @ M_chunkstart              (k_scan, block-private M slice)
//   scale = rowsum(tril(PQ PK^T)) + PQ.z_chunkstart + 1e-5   (k_gram + k_scale)

constexpr int Bn  = 8;
constexpr int Sn  = 2048;
constexpr int Cn  = 512;
constexpr int Tn  = 128;
constexpr int NCn = 16;                         // Sn / Tn
constexpr float DKf = 0.04419417382415922f;     // 1/sqrt(512)

__device__ __forceinline__ float phi_f(float u) {
  float s = u * DKf;
  return s > 0.0f ? s + 1.0f : __expf(s);       // elu(s)+1
}

// ---------------- K1: projections -------------------------------------------
// out_z[m,n] = transform(sum_k x[m,k] * W_z[n,k]); z in {q,k,v}
// 128x128 tile, 256 threads, 8x8 per thread, K-tile 8.
__global__ __launch_bounds__(256) void k_proj(
    const float* __restrict__ x, const float* __restrict__ Wq,
    const float* __restrict__ Wk, const float* __restrict__ Wv,
    float* __restrict__ PQ, float* __restrict__ PK, float* __restrict__ Vv)
{
  const int z = blockIdx.z;
  const float* __restrict__ W = (z == 0) ? Wq : (z == 1 ? Wk : Wv);
  float* __restrict__ out = (z == 0) ? PQ : (z == 1 ? PK : Vv);
  const int m0 = blockIdx.y * 128;
  const int n0 = blockIdx.x * 128;
  __shared__ float xs[8][132];   // [k][m] transposed; +4 pad keeps f4 align, 2-way banks (free)
  __shared__ float ws[8][132];
  const int t  = threadIdx.x;
  const int lr = t >> 1, lk = (t & 1) * 4;
  const int tm = t >> 4, tn = t & 15;
  float acc[8][8];
#pragma unroll
  for (int i = 0; i < 8; ++i)
#pragma unroll
    for (int j = 0; j < 8; ++j) acc[i][j] = 0.0f;
  const float* xp = x + (size_t)(m0 + lr) * Cn + lk;
  const float* wp = W + (size_t)(n0 + lr) * Cn + lk;
  for (int k0 = 0; k0 < Cn; k0 += 8) {
    float4 xa = *(const float4*)(xp + k0);
    float4 wa = *(const float4*)(wp + k0);
    __syncthreads();
    xs[lk + 0][lr] = xa.x; xs[lk + 1][lr] = xa.y; xs[lk + 2][lr] = xa.z; xs[lk + 3][lr] = xa.w;
    ws[lk + 0][lr] = wa.x; ws[lk + 1][lr] = wa.y; ws[lk + 2][lr] = wa.z; ws[lk + 3][lr] = wa.w;
    __syncthreads();
#pragma unroll
    for (int k = 0; k < 8; ++k) {
      float a[8], b[8];
      *(float4*)(a)     = *(const float4*)&xs[k][tm * 8];
      *(float4*)(a + 4) = *(const float4*)&xs[k][tm * 8 + 4];
      *(float4*)(b)     = *(const float4*)&ws[k][tn * 8];
      *(float4*)(b + 4) = *(const float4*)&ws[k][tn * 8 + 4];
#pragma unroll
      for (int i = 0; i < 8; ++i)
#pragma unroll
        for (int j = 0; j < 8; ++j) acc[i][j] = fmaf(a[i], b[j], acc[i][j]);
    }
  }
#pragma unroll
  for (int i = 0; i < 8; ++i) {
    float* orow = out + (size_t)(m0 + tm * 8 + i) * Cn + n0 + tn * 8;
    float4 o0, o1;
    if (z < 2) {
      o0.x = phi_f(acc[i][0]); o0.y = phi_f(acc[i][1]); o0.z = phi_f(acc[i][2]); o0.w = phi_f(acc[i][3]);
      o1.x = phi_f(acc[i][4]); o1.y = phi_f(acc[i][5]); o1.z = phi_f(acc[i][6]); o1.w = phi_f(acc[i][7]);
    } else {
      o0.x = acc[i][0]; o0.y = acc[i][1]; o0.z = acc[i][2]; o0.w = acc[i][3];
      o1.x = acc[i][4]; o1.y = acc[i][5]; o1.z = acc[i][6]; o1.w = acc[i][7];
    }
    *(float4*)orow       = o0;
    *(float4*)(orow + 4) = o1;
  }
}

// ---------------- K2a: A = tril(PQ_c PK_c^T), rowsum -> scale ----------------
// grid (2, NC, B): 64-row slice of the 128x128 chunk Gram matrix. K = 512.
__global__ __launch_bounds__(256) void k_gram(
    const float* __restrict__ PQ, const float* __restrict__ PK,
    float* __restrict__ A, float* __restrict__ scale)
{
  const int b = blockIdx.z, ch = blockIdx.y;
  const int i0 = blockIdx.x * 64;
  const int t0 = ch * Tn;
  __shared__ float qs[8][68];    // [k][row 0..63]
  __shared__ float ks[8][132];   // [k][col 0..127]
  const int t  = threadIdx.x;
  const int rg = t >> 5, cg = t & 31;              // 8x4 thread tile over 64x128
  const int lr = t >> 1, lk = (t & 1) * 4;
  const int lrq = (t < 128) ? (t >> 1) : 0;
  float acc[8][4];
#pragma unroll
  for (int i = 0; i < 8; ++i)
#pragma unroll
    for (int j = 0; j < 4; ++j) acc[i][j] = 0.0f;
  const float* kp = PK + (size_t)(b * Sn + t0 + lr) * Cn + lk;
  const float* qp = PQ + (size_t)(b * Sn + t0 + i0 + lrq) * Cn + lk;
  for (int k0 = 0; k0 < Cn; k0 += 8) {
    float4 ka = *(const float4*)(kp + k0);
    float4 qa = make_float4(0.f, 0.f, 0.f, 0.f);
    if (t < 128) qa = *(const float4*)(qp + k0);
    __syncthreads();
    ks[lk + 0][lr] = ka.x; ks[lk + 1][lr] = ka.y; ks[lk + 2][lr] = ka.z; ks[lk + 3][lr] = ka.w;
    if (t < 128) {
      qs[lk + 0][lrq] = qa.x; qs[lk + 1][lrq] = qa.y; qs[lk + 2][lrq] = qa.z; qs[lk + 3][lrq] = qa.w;
    }
    __syncthreads();
#pragma unroll
    for (int k = 0; k < 8; ++k) {
      float a[8], bb[4];
      *(float4*)(a)     = *(const float4*)&qs[k][rg * 8];
      *(float4*)(a + 4) = *(const float4*)&qs[k][rg * 8 + 4];
      *(float4*)(bb)    = *(const float4*)&ks[k][cg * 4];
#pragma unroll
      for (int i = 0; i < 8; ++i)
#pragma unroll
        for (int j = 0; j < 4; ++j) acc[i][j] = fmaf(a[i], bb[j], acc[i][j]);
    }
  }
  float rs[8];
#pragma unroll
  for (int ii = 0; ii < 8; ++ii) {
    const int irow = i0 + rg * 8 + ii;             // chunk-local row
    float r = 0.f;
#pragma unroll
    for (int jj = 0; jj < 4; ++jj) {
      const int jcol = cg * 4 + jj;                // chunk-local col
      float v = (jcol <= irow) ? acc[ii][jj] : 0.0f;
      acc[ii][jj] = v;
      r += v;
    }
    rs[ii] = r;
    float4 av = make_float4(acc[ii][0], acc[ii][1], acc[ii][2], acc[ii][3]);
    *(float4*)&A[(((size_t)b * NCn + ch) * Tn + irow) * Tn + cg * 4] = av;
  }
#pragma unroll
  for (int ii = 0; ii < 8; ++ii) {
    float r = rs[ii];
    r += __shfl_xor(r, 1);  r += __shfl_xor(r, 2);  r += __shfl_xor(r, 4);
    r += __shfl_xor(r, 8);  r += __shfl_xor(r, 16);
    if (cg == 0) scale[(size_t)b * Sn + t0 + i0 + rg * 8 + ii] = r;
  }
}

// ---------------- K2b: intra = A @ V_c  -> d_out (undivided) -----------------
// grid (4, NC, B): 128 rows x 128 d cols, K = 128.
__global__ __launch_bounds__(256) void k_av(
    const float* __restrict__ A, const float* __restrict__ Vv,
    float* __restrict__ out)
{
  const int b = blockIdx.z, ch = blockIdx.y, d0 = blockIdx.x * 128;
  const int t0 = ch * Tn;
  __shared__ float as[8][132];   // [kj][row] transposed
  __shared__ float vs[8][136];   // [kj][d] direct (stride%4==0 for f4)
  const int t  = threadIdx.x;
  const int tm = t >> 4, tn = t & 15;
  const int lr = t >> 1, lj = (t & 1) * 4;
  const int jr = t >> 5, dq = (t & 31) * 4;
  float acc[8][8];
#pragma unroll
  for (int i = 0; i < 8; ++i)
#pragma unroll
    for (int j = 0; j < 8; ++j) acc[i][j] = 0.0f;
  const float* ap = A + (((size_t)b * NCn + ch) * Tn + lr) * Tn + lj;
  const float* vp = Vv + (size_t)(b * Sn + t0 + jr) * Cn + d0 + dq;
  for (int j0 = 0; j0 < Tn; j0 += 8) {
    float4 aa = *(const float4*)(ap + j0);
    float4 vv = *(const float4*)(vp + (size_t)j0 * Cn);
    __syncthreads();
    as[lj + 0][lr] = aa.x; as[lj + 1][lr] = aa.y; as[lj + 2][lr] = aa.z; as[lj + 3][lr] = aa.w;
    *(float4*)&vs[jr][dq] = vv;
    __syncthreads();
#pragma unroll
    for (int k = 0; k < 8; ++k) {
      float a[8], bb[8];
      *(float4*)(a)      = *(const float4*)&as[k][tm * 8];
      *(float4*)(a + 4)  = *(const float4*)&as[k][tm * 8 + 4];
      *(float4*)(bb)     = *(const float4*)&vs[k][tn * 8];
      *(float4*)(bb + 4) = *(const float4*)&vs[k][tn * 8 + 4];
#pragma unroll
      for (int i = 0; i < 8; ++i)
#pragma unroll
        for (int j = 0; j < 8; ++j) acc[i][j] = fmaf(a[i], bb[j], acc[i][j]);
    }
  }
#pragma unroll
  for (int i = 0; i < 8; ++i) {
    float* orow = out + (size_t)(b * Sn + t0 + tm * 8 + i) * Cn + d0 + tn * 8;
    *(float4*)orow       = make_float4(acc[i][0], acc[i][1], acc[i][2], acc[i][3]);
    *(float4*)(orow + 4) = make_float4(acc[i][4], acc[i][5], acc[i][6], acc[i][7]);
  }
}

// ---------------- Kz: z running sums + scale finalize ------------------------
__global__ __launch_bounds__(512) void k_zsum(const float* __restrict__ PK, float* __restrict__ zsum) {
  const int b = blockIdx.y, ch = blockIdx.x, c = threadIdx.x;
  const float* p = PK + (size_t)(b * Sn + ch * Tn) * Cn + c;
  float s = 0.f;
  for (int j = 0; j < Tn; ++j) s += p[(size_t)j * Cn];
  zsum[((size_t)b * NCn + ch) * Cn + c] = s;
}

__global__ __launch_bounds__(512) void k_zpre(const float* __restrict__ zsum, float* __restrict__ zpre) {
  const int b = blockIdx.x, c = threadIdx.x;
  float run = 0.f;
  for (int ch = 0; ch < NCn; ++ch) {
    zpre[((size_t)b * NCn + ch) * Cn + c] = run;
    run += zsum[((size_t)b * NCn + ch) * Cn + c];
  }
}

__global__ __launch_bounds__(256) void k_scale(const float* __restrict__ PQ,
                                               const float* __restrict__ zpre,
                                               float* __restrict__ scale) {
  const int b = blockIdx.y;
  const int w = threadIdx.x >> 6, lane = threadIdx.x & 63;
  const int row = blockIdx.x * 4 + w;
  const int ch = row >> 7;
  const float* pq = PQ + (size_t)(b * Sn + row) * Cn + lane * 8;
  const float* zp = zpre + ((size_t)b * NCn + ch) * Cn + lane * 8;
  float4 p0 = *(const float4*)pq, p1 = *(const float4*)(pq + 4);
  float4 z0 = *(const float4*)zp, z1 = *(const float4*)(zp + 4);
  float d = p0.x * z0.x + p0.y * z0.y + p0.z * z0.z + p0.w * z0.w
          + p1.x * z1.x + p1.y * z1.y + p1.z * z1.z + p1.w * z1.w;
#pragma unroll
  for (int off = 32; off > 0; off >>= 1) d += __shfl_xor(d, off);
  if (lane == 0) scale[(size_t)b * Sn + row] += d + 1e-5f;
}

// ---------------- K3: inter = PQ @ M_start, finalize; M += PK^T V ------------
// grid (32, B): block owns a 16-wide d-slice of M for one batch; chunks sequential
// within the block (M is block-private -> no grid sync, no M materialization).
__global__ __launch_bounds__(256) void k_scan(
    const float* __restrict__ PQ, const float* __restrict__ PK,
    const float* __restrict__ Vv, const float* __restrict__ scale,
    float* __restrict__ out)
{
  __shared__ float Msh[512 * 16];   // M slice, fp32, persistent across chunks (32 KB)
  __shared__ float sbuf[8 * 516];   // union: phaseA pqt[16][132] / phaseB pk8[8][516]
  __shared__ float vsb[128 * 16];   // V chunk slice
  const int t  = threadIdx.x;
  const int b  = blockIdx.y, d0 = blockIdx.x * 16;
  for (int i = t; i < 512 * 16; i += 256) Msh[i] = 0.f;
  const int tgA = t >> 3, dgA = t & 7;   // phase A: 4 rows x 2 d per thread
  const int cgB = t >> 2, dgB = t & 3;   // phase B: 8 c x 4 d per thread
  for (int ch = 0; ch < NCn; ++ch) {
    const int t0 = ch * Tn;
    // -------- phase A: inter = PQ_chunk @ M, then finalize output ----------
    float accA[4][2] = {{0.f,0.f},{0.f,0.f},{0.f,0.f},{0.f,0.f}};
    if (ch > 0) {
      for (int cb = 0; cb < 32; ++cb) {
        __syncthreads();   // guards sbuf reuse (prev cb / prev chunk phase B); also Msh init->read
#pragma unroll
        for (int e = 0; e < 2; ++e) {
          int idx = t + e * 256;           // 0..511
          int tt = idx >> 2, c4 = (idx & 3) * 4;
          float4 q = *(const float4*)&PQ[(size_t)(b * Sn + t0 + tt) * Cn + cb * 16 + c4];
          sbuf[(c4 + 0) * 132 + tt] = q.x; sbuf[(c4 + 1) * 132 + tt] = q.y;
          sbuf[(c4 + 2) * 132 + tt] = q.z; sbuf[(c4 + 3) * 132 + tt] = q.w;
        }
        __syncthreads();
#pragma unroll
        for (int c = 0; c < 16; ++c) {
          float4 a  = *(const float4*)&sbuf[c * 132 + tgA * 4];
          float2 mv = *(const float2*)&Msh[(cb * 16 + c) * 16 + dgA * 2];
          accA[0][0] = fmaf(a.x, mv.x, accA[0][0]); accA[0][1] = fmaf(a.x, mv.y, accA[0][1]);
          accA[1][0] = fmaf(a.y, mv.x, accA[1][0]); accA[1][1] = fmaf(a.y, mv.y, accA[1][1]);
          accA[2][0] = fmaf(a.z, mv.x, accA[2][0]); accA[2][1] = fmaf(a.z, mv.y, accA[2][1]);
          accA[3][0] = fmaf(a.w, mv.x, accA[3][0]); accA[3][1] = fmaf(a.w, mv.y, accA[3][1]);
        }
      }
    }
#pragma unroll
    for (int i = 0; i < 4; ++i) {
      const int row = t0 + tgA * 4 + i;
      const float sc = scale[(size_t)b * Sn + row];
      const size_t o = (size_t)(b * Sn + row) * Cn + d0 + dgA * 2;
      float2 cur = *(const float2*)&out[o];
      cur.x = (cur.x + accA[i][0]) / sc;
      cur.y = (cur.y + accA[i][1]) / sc;
      *(float2*)&out[o] = cur;
    }
    // -------- phase B: M += PK_chunk^T @ V_chunk (slice) -------------------
    if (ch < NCn - 1) {
      float accB[8][4];
#pragma unroll
      for (int i = 0; i < 8; ++i)
#pragma unroll
        for (int jj = 0; jj < 4; ++jj) accB[i][jj] = 0.f;
      __syncthreads();
#pragma unroll
      for (int e = 0; e < 2; ++e) {
        int idx = t + e * 256;
        int j = idx >> 2, d4 = (idx & 3) * 4;
        *(float4*)&vsb[j * 16 + d4] =
            *(const float4*)&Vv[(size_t)(b * Sn + t0 + j) * Cn + d0 + d4];
      }
      for (int jb = 0; jb < 16; ++jb) {
        __syncthreads();   // sbuf reuse + (jb==0) vsb visibility
#pragma unroll
        for (int e = 0; e < 4; ++e) {
          int idx = t + e * 256;           // 0..1023
          int j = idx >> 7, cq = (idx & 127) * 4;
          *(float4*)&sbuf[j * 516 + cq] =
              *(const float4*)&PK[(size_t)(b * Sn + t0 + jb * 8 + j) * Cn + cq];
        }
        __syncthreads();
#pragma unroll
        for (int j = 0; j < 8; ++j) {
          float a[8], bb[4];
          *(float4*)(a)     = *(const float4*)&sbuf[j * 516 + cgB * 8];
          *(float4*)(a + 4) = *(const float4*)&sbuf[j * 516 + cgB * 8 + 4];
          *(float4*)(bb)    = *(const float4*)&vsb[(jb * 8 + j) * 16 + dgB * 4];
#pragma unroll
          for (int i = 0; i < 8; ++i)
#pragma unroll
            for (int jj = 0; jj < 4; ++jj) accB[i][jj] = fmaf(a[i], bb[jj], accB[i][jj]);
        }
      }
#pragma unroll
      for (int i = 0; i < 8; ++i)
#pragma unroll
        for (int jj = 0; jj < 4; ++jj)
          Msh[(cgB * 8 + i) * 16 + dgB * 4 + jj] += accB[i][jj];
      // next chunk's phase A first sync orders this += before Msh reads
    }
  }
}

// ---------------- launch -----------------------------------------------------
extern "C" void kernel_launch(void* const* d_in, const int* in_sizes, int n_in,
                              void* d_out, int out_size, void* d_ws, size_t ws_size,
                              hipStream_t stream)
{
  const float* x  = (const float*)d_in[0];
  const float* Wq = (const float*)d_in[1];
  const float* Wk = (const float*)d_in[2];
  const float* Wv = (const float*)d_in[3];
  float* out = (float*)d_out;
  float* ws  = (float*)d_ws;

  float* PQ    = ws;                                   // 8.39M floats
  float* PK    = PQ + (size_t)Bn * Sn * Cn;
  float* Vv    = PK + (size_t)Bn * Sn * Cn;
  float* A     = Vv + (size_t)Bn * Sn * Cn;            // B*NC*T*T = 2.10M
  float* zsum  = A + (size_t)Bn * NCn * Tn * Tn;       // 65536
  float* zpre  = zsum + (size_t)Bn * NCn * Cn;         // 65536
  float* scale = zpre + (size_t)Bn * NCn * Cn;         // 16384
  (void)ws_size; (void)in_sizes; (void)n_in; (void)out_size;

  hipLaunchKernelGGL(k_proj, dim3(Cn / 128, (Bn * Sn) / 128, 3), dim3(256), 0, stream,
                     x, Wq, Wk, Wv, PQ, PK, Vv);
  hipLaunchKernelGGL(k_zsum, dim3(NCn, Bn), dim3(512), 0, stream, PK, zsum);
  hipLaunchKernelGGL(k_zpre, dim3(Bn), dim3(512), 0, stream, zsum, zpre);
  hipLaunchKernelGGL(k_gram, dim3(2, NCn, Bn), dim3(256), 0, stream, PQ, PK, A, scale);
  hipLaunchKernelGGL(k_scale, dim3(Sn / 4, Bn), dim3(256), 0, stream, PQ, zpre, scale);
  hipLaunchKernelGGL(k_av, dim3(Cn / 128, NCn, Bn), dim3(256), 0, stream, A, Vv, out);
  hipLaunchKernelGGL(k_scan, dim3(Cn / 16, Bn), dim3(256), 0, stream, PQ, PK, Vv, scale, out);
}

// Round 2
// 680.508 us; speedup vs baseline: 1.4271x; 1.4271x over previous
//
#include <hip/hip_runtime.h>

// LinearAttentionCell: chunked linear attention, fp32, fully-parallel scan.
// y[b,t,:] = (phiQ_t . M_t) / (phiQ_t . z_t + 1e-5),
//   M_t = sum_{t'<=t} phiK_{t'} v_{t'}^T,  z_t = sum_{t'<=t} phiK_{t'}
// Chunked (T=128):
//   intra = tril(PQ_c PK_c^T) @ V_c            (k_gram + k_av)
//   KV_c  = PK_c^T V_c                          (k_kv, parallel over chunks)
//   Mpre  = exclusive chunk prefix of KV        (k_prefix, in-place)
//   out   = (intra + PQ_c @ Mpre_c) / scale     (k_inter)
//   scale = rowsum(tril(PQ PK^T)) + PQ.zpre + 1e-5   (k_gram + k_scale)

constexpr int Bn  = 8;
constexpr int Sn  = 2048;
constexpr int Cn  = 512;
constexpr int Tn  = 128;
constexpr int NCn = 16;                         // Sn / Tn
constexpr float DKf = 0.04419417382415922f;     // 1/sqrt(512)

__device__ __forceinline__ float phi_f(float u) {
  float s = u * DKf;
  return s > 0.0f ? s + 1.0f : __expf(s);       // elu(s)+1
}

// ---------------- K1: projections -------------------------------------------
// out_z[m,n] = transform(sum_k x[m,k] * W_z[n,k]); z in {q,k,v}
// 128x128 tile, 256 threads, 8x8 per thread, K-tile 8.
__global__ __launch_bounds__(256) void k_proj(
    const float* __restrict__ x, const float* __restrict__ Wq,
    const float* __restrict__ Wk, const float* __restrict__ Wv,
    float* __restrict__ PQ, float* __restrict__ PK, float* __restrict__ Vv)
{
  const int z = blockIdx.z;
  const float* __restrict__ W = (z == 0) ? Wq : (z == 1 ? Wk : Wv);
  float* __restrict__ out = (z == 0) ? PQ : (z == 1 ? PK : Vv);
  const int m0 = blockIdx.y * 128;
  const int n0 = blockIdx.x * 128;
  __shared__ float xs[8][132];   // [k][m] transposed
  __shared__ float ws[8][132];
  const int t  = threadIdx.x;
  const int lr = t >> 1, lk = (t & 1) * 4;
  const int tm = t >> 4, tn = t & 15;
  float acc[8][8];
#pragma unroll
  for (int i = 0; i < 8; ++i)
#pragma unroll
    for (int j = 0; j < 8; ++j) acc[i][j] = 0.0f;
  const float* xp = x + (size_t)(m0 + lr) * Cn + lk;
  const float* wp = W + (size_t)(n0 + lr) * Cn + lk;
  for (int k0 = 0; k0 < Cn; k0 += 8) {
    float4 xa = *(const float4*)(xp + k0);
    float4 wa = *(const float4*)(wp + k0);
    __syncthreads();
    xs[lk + 0][lr] = xa.x; xs[lk + 1][lr] = xa.y; xs[lk + 2][lr] = xa.z; xs[lk + 3][lr] = xa.w;
    ws[lk + 0][lr] = wa.x; ws[lk + 1][lr] = wa.y; ws[lk + 2][lr] = wa.z; ws[lk + 3][lr] = wa.w;
    __syncthreads();
#pragma unroll
    for (int k = 0; k < 8; ++k) {
      float a[8], b[8];
      *(float4*)(a)     = *(const float4*)&xs[k][tm * 8];
      *(float4*)(a + 4) = *(const float4*)&xs[k][tm * 8 + 4];
      *(float4*)(b)     = *(const float4*)&ws[k][tn * 8];
      *(float4*)(b + 4) = *(const float4*)&ws[k][tn * 8 + 4];
#pragma unroll
      for (int i = 0; i < 8; ++i)
#pragma unroll
        for (int j = 0; j < 8; ++j) acc[i][j] = fmaf(a[i], b[j], acc[i][j]);
    }
  }
#pragma unroll
  for (int i = 0; i < 8; ++i) {
    float* orow = out + (size_t)(m0 + tm * 8 + i) * Cn + n0 + tn * 8;
    float4 o0, o1;
    if (z < 2) {
      o0.x = phi_f(acc[i][0]); o0.y = phi_f(acc[i][1]); o0.z = phi_f(acc[i][2]); o0.w = phi_f(acc[i][3]);
      o1.x = phi_f(acc[i][4]); o1.y = phi_f(acc[i][5]); o1.z = phi_f(acc[i][6]); o1.w = phi_f(acc[i][7]);
    } else {
      o0.x = acc[i][0]; o0.y = acc[i][1]; o0.z = acc[i][2]; o0.w = acc[i][3];
      o1.x = acc[i][4]; o1.y = acc[i][5]; o1.z = acc[i][6]; o1.w = acc[i][7];
    }
    *(float4*)orow       = o0;
    *(float4*)(orow + 4) = o1;
  }
}

// ---------------- K2a: A = tril(PQ_c PK_c^T), rowsum -> scale ----------------
// grid (2, NC, B): 64-row slice of the 128x128 chunk Gram matrix. K = 512.
__global__ __launch_bounds__(256) void k_gram(
    const float* __restrict__ PQ, const float* __restrict__ PK,
    float* __restrict__ A, float* __restrict__ scale)
{
  const int b = blockIdx.z, ch = blockIdx.y;
  const int i0 = blockIdx.x * 64;
  const int t0 = ch * Tn;
  __shared__ float qs[8][68];    // [k][row 0..63]
  __shared__ float ks[8][132];   // [k][col 0..127]
  const int t  = threadIdx.x;
  const int rg = t >> 5, cg = t & 31;              // 8x4 thread tile over 64x128
  const int lr = t >> 1, lk = (t & 1) * 4;
  const int lrq = (t < 128) ? (t >> 1) : 0;
  float acc[8][4];
#pragma unroll
  for (int i = 0; i < 8; ++i)
#pragma unroll
    for (int j = 0; j < 4; ++j) acc[i][j] = 0.0f;
  const float* kp = PK + (size_t)(b * Sn + t0 + lr) * Cn + lk;
  const float* qp = PQ + (size_t)(b * Sn + t0 + i0 + lrq) * Cn + lk;
  for (int k0 = 0; k0 < Cn; k0 += 8) {
    float4 ka = *(const float4*)(kp + k0);
    float4 qa = make_float4(0.f, 0.f, 0.f, 0.f);
    if (t < 128) qa = *(const float4*)(qp + k0);
    __syncthreads();
    ks[lk + 0][lr] = ka.x; ks[lk + 1][lr] = ka.y; ks[lk + 2][lr] = ka.z; ks[lk + 3][lr] = ka.w;
    if (t < 128) {
      qs[lk + 0][lrq] = qa.x; qs[lk + 1][lrq] = qa.y; qs[lk + 2][lrq] = qa.z; qs[lk + 3][lrq] = qa.w;
    }
    __syncthreads();
#pragma unroll
    for (int k = 0; k < 8; ++k) {
      float a[8], bb[4];
      *(float4*)(a)     = *(const float4*)&qs[k][rg * 8];
      *(float4*)(a + 4) = *(const float4*)&qs[k][rg * 8 + 4];
      *(float4*)(bb)    = *(const float4*)&ks[k][cg * 4];
#pragma unroll
      for (int i = 0; i < 8; ++i)
#pragma unroll
        for (int j = 0; j < 4; ++j) acc[i][j] = fmaf(a[i], bb[j], acc[i][j]);
    }
  }
  float rs[8];
#pragma unroll
  for (int ii = 0; ii < 8; ++ii) {
    const int irow = i0 + rg * 8 + ii;             // chunk-local row
    float r = 0.f;
#pragma unroll
    for (int jj = 0; jj < 4; ++jj) {
      const int jcol = cg * 4 + jj;                // chunk-local col
      float v = (jcol <= irow) ? acc[ii][jj] : 0.0f;
      acc[ii][jj] = v;
      r += v;
    }
    rs[ii] = r;
    float4 av = make_float4(acc[ii][0], acc[ii][1], acc[ii][2], acc[ii][3]);
    *(float4*)&A[(((size_t)b * NCn + ch) * Tn + irow) * Tn + cg * 4] = av;
  }
#pragma unroll
  for (int ii = 0; ii < 8; ++ii) {
    float r = rs[ii];
    r += __shfl_xor(r, 1);  r += __shfl_xor(r, 2);  r += __shfl_xor(r, 4);
    r += __shfl_xor(r, 8);  r += __shfl_xor(r, 16);
    if (cg == 0) scale[(size_t)b * Sn + t0 + i0 + rg * 8 + ii] = r;
  }
}

// ---------------- K2b: intra = A @ V_c  -> d_out (undivided) -----------------
// grid (4, NC, B): 128 rows x 128 d cols, K = 128.
__global__ __launch_bounds__(256) void k_av(
    const float* __restrict__ A, const float* __restrict__ Vv,
    float* __restrict__ out)
{
  const int b = blockIdx.z, ch = blockIdx.y, d0 = blockIdx.x * 128;
  const int t0 = ch * Tn;
  __shared__ float as[8][132];   // [kj][row] transposed
  __shared__ float vs[8][136];   // [kj][d] direct
  const int t  = threadIdx.x;
  const int tm = t >> 4, tn = t & 15;
  const int lr = t >> 1, lj = (t & 1) * 4;
  const int jr = t >> 5, dq = (t & 31) * 4;
  float acc[8][8];
#pragma unroll
  for (int i = 0; i < 8; ++i)
#pragma unroll
    for (int j = 0; j < 8; ++j) acc[i][j] = 0.0f;
  const float* ap = A + (((size_t)b * NCn + ch) * Tn + lr) * Tn + lj;
  const float* vp = Vv + (size_t)(b * Sn + t0 + jr) * Cn + d0 + dq;
  for (int j0 = 0; j0 < Tn; j0 += 8) {
    float4 aa = *(const float4*)(ap + j0);
    float4 vv = *(const float4*)(vp + (size_t)j0 * Cn);
    __syncthreads();
    as[lj + 0][lr] = aa.x; as[lj + 1][lr] = aa.y; as[lj + 2][lr] = aa.z; as[lj + 3][lr] = aa.w;
    *(float4*)&vs[jr][dq] = vv;
    __syncthreads();
#pragma unroll
    for (int k = 0; k < 8; ++k) {
      float a[8], bb[8];
      *(float4*)(a)      = *(const float4*)&as[k][tm * 8];
      *(float4*)(a + 4)  = *(const float4*)&as[k][tm * 8 + 4];
      *(float4*)(bb)     = *(const float4*)&vs[k][tn * 8];
      *(float4*)(bb + 4) = *(const float4*)&vs[k][tn * 8 + 4];
#pragma unroll
      for (int i = 0; i < 8; ++i)
#pragma unroll
        for (int j = 0; j < 8; ++j) acc[i][j] = fmaf(a[i], bb[j], acc[i][j]);
    }
  }
#pragma unroll
  for (int i = 0; i < 8; ++i) {
    float* orow = out + (size_t)(b * Sn + t0 + tm * 8 + i) * Cn + d0 + tn * 8;
    *(float4*)orow       = make_float4(acc[i][0], acc[i][1], acc[i][2], acc[i][3]);
    *(float4*)(orow + 4) = make_float4(acc[i][4], acc[i][5], acc[i][6], acc[i][7]);
  }
}

// ---------------- Kz: z running sums + scale finalize ------------------------
__global__ __launch_bounds__(512) void k_zsum(const float* __restrict__ PK, float* __restrict__ zsum) {
  const int b = blockIdx.y, ch = blockIdx.x, c = threadIdx.x;
  const float* p = PK + (size_t)(b * Sn + ch * Tn) * Cn + c;
  float s = 0.f;
  for (int j = 0; j < Tn; ++j) s += p[(size_t)j * Cn];
  zsum[((size_t)b * NCn + ch) * Cn + c] = s;
}

__global__ __launch_bounds__(512) void k_zpre(const float* __restrict__ zsum, float* __restrict__ zpre) {
  const int b = blockIdx.x, c = threadIdx.x;
  float run = 0.f;
  for (int ch = 0; ch < NCn; ++ch) {
    zpre[((size_t)b * NCn + ch) * Cn + c] = run;
    run += zsum[((size_t)b * NCn + ch) * Cn + c];
  }
}

__global__ __launch_bounds__(256) void k_scale(const float* __restrict__ PQ,
                                               const float* __restrict__ zpre,
                                               float* __restrict__ scale) {
  const int b = blockIdx.y;
  const int w = threadIdx.x >> 6, lane = threadIdx.x & 63;
  const int row = blockIdx.x * 4 + w;
  const int ch = row >> 7;
  const float* pq = PQ + (size_t)(b * Sn + row) * Cn + lane * 8;
  const float* zp = zpre + ((size_t)b * NCn + ch) * Cn + lane * 8;
  float4 p0 = *(const float4*)pq, p1 = *(const float4*)(pq + 4);
  float4 z0 = *(const float4*)zp, z1 = *(const float4*)(zp + 4);
  float d = p0.x * z0.x + p0.y * z0.y + p0.z * z0.z + p0.w * z0.w
          + p1.x * z1.x + p1.y * z1.y + p1.z * z1.z + p1.w * z1.w;
#pragma unroll
  for (int off = 32; off > 0; off >>= 1) d += __shfl_xor(d, off);
  if (lane == 0) scale[(size_t)b * Sn + row] += d + 1e-5f;
}

// ---------------- K3a: KV_c = PK_c^T @ V_c -----------------------------------
// grid (16, NC, B): 4x4 tiles of the 512x512 chunk outer-product sum, K = 128.
// Both operands stage as direct rows (A[m=c][k=j] = PK[j][c], B[k=j][n=d] = V[j][d]).
__global__ __launch_bounds__(256) void k_kv(
    const float* __restrict__ PK, const float* __restrict__ Vv,
    float* __restrict__ KV)
{
  const int b = blockIdx.z, ch = blockIdx.y;
  const int c0 = (blockIdx.x >> 2) * 128, d0 = (blockIdx.x & 3) * 128;
  const int t0 = ch * Tn;
  __shared__ float ks[8][132];   // [j][c]
  __shared__ float vs[8][132];   // [j][d]
  const int t  = threadIdx.x;
  const int tm = t >> 4, tn = t & 15;
  const int jr = t >> 5, cq = (t & 31) * 4;
  float acc[8][8];
#pragma unroll
  for (int i = 0; i < 8; ++i)
#pragma unroll
    for (int j = 0; j < 8; ++j) acc[i][j] = 0.0f;
  const float* kp = PK + (size_t)(b * Sn + t0 + jr) * Cn + c0 + cq;
  const float* vp = Vv + (size_t)(b * Sn + t0 + jr) * Cn + d0 + cq;
  for (int j0 = 0; j0 < Tn; j0 += 8) {
    float4 ka = *(const float4*)(kp + (size_t)j0 * Cn);
    float4 va = *(const float4*)(vp + (size_t)j0 * Cn);
    __syncthreads();
    *(float4*)&ks[jr][cq] = ka;
    *(float4*)&vs[jr][cq] = va;
    __syncthreads();
#pragma unroll
    for (int k = 0; k < 8; ++k) {
      float a[8], bb[8];
      *(float4*)(a)      = *(const float4*)&ks[k][tm * 8];
      *(float4*)(a + 4)  = *(const float4*)&ks[k][tm * 8 + 4];
      *(float4*)(bb)     = *(const float4*)&vs[k][tn * 8];
      *(float4*)(bb + 4) = *(const float4*)&vs[k][tn * 8 + 4];
#pragma unroll
      for (int i = 0; i < 8; ++i)
#pragma unroll
        for (int j = 0; j < 8; ++j) acc[i][j] = fmaf(a[i], bb[j], acc[i][j]);
    }
  }
#pragma unroll
  for (int i = 0; i < 8; ++i) {
    float* orow = KV + (((size_t)(b * NCn + ch)) * Cn + c0 + tm * 8 + i) * Cn + d0 + tn * 8;
    *(float4*)orow       = make_float4(acc[i][0], acc[i][1], acc[i][2], acc[i][3]);
    *(float4*)(orow + 4) = make_float4(acc[i][4], acc[i][5], acc[i][6], acc[i][7]);
  }
}

// ---------------- K3b: exclusive chunk prefix of KV, in place ----------------
// Each thread owns one (c, d4) column across all 16 chunks. grid (256, B).
__global__ __launch_bounds__(256) void k_prefix(float* __restrict__ KV)
{
  const int b = blockIdx.y;
  const size_t base = (size_t)b * NCn * Cn * Cn
                    + (size_t)(blockIdx.x * 256 + threadIdx.x) * 4;
  float4 run = make_float4(0.f, 0.f, 0.f, 0.f);
  for (int ch = 0; ch < NCn; ++ch) {
    float4* p = (float4*)&KV[base + (size_t)ch * Cn * Cn];
    float4 cur = *p;
    *p = run;
    run.x += cur.x; run.y += cur.y; run.z += cur.z; run.w += cur.w;
  }
}

// ---------------- K3c: out = (out + PQ_c @ Mpre_c) / scale -------------------
// grid (4, NC, B): 128 rows x 128 d, K = 512. ch==0 has Mpre=0 -> divide only.
__global__ __launch_bounds__(256) void k_inter(
    const float* __restrict__ PQ, const float* __restrict__ KV,
    const float* __restrict__ scale, float* __restrict__ out)
{
  const int b = blockIdx.z, ch = blockIdx.y, d0 = blockIdx.x * 128;
  const int t0 = ch * Tn;
  __shared__ float qs[8][132];   // [c][t] transposed
  __shared__ float ms[8][136];   // [c][d] direct
  const int t  = threadIdx.x;
  const int tm = t >> 4, tn = t & 15;
  float acc[8][8];
#pragma unroll
  for (int i = 0; i < 8; ++i)
#pragma unroll
    for (int j = 0; j < 8; ++j) acc[i][j] = 0.0f;
  if (ch > 0) {
    const int lr = t >> 1, lc = (t & 1) * 4;
    const int jr = t >> 5, dq = (t & 31) * 4;
    const float* qp = PQ + (size_t)(b * Sn + t0 + lr) * Cn + lc;
    const float* mp = KV + (((size_t)(b * NCn + ch)) * Cn + jr) * Cn + d0 + dq;
    for (int c0 = 0; c0 < Cn; c0 += 8) {
      float4 qa = *(const float4*)(qp + c0);
      float4 ma = *(const float4*)(mp + (size_t)c0 * Cn);
      __syncthreads();
      qs[lc + 0][lr] = qa.x; qs[lc + 1][lr] = qa.y; qs[lc + 2][lr] = qa.z; qs[lc + 3][lr] = qa.w;
      *(float4*)&ms[jr][dq] = ma;
      __syncthreads();
#pragma unroll
      for (int k = 0; k < 8; ++k) {
        float a[8], bb[8];
        *(float4*)(a)      = *(const float4*)&qs[k][tm * 8];
        *(float4*)(a + 4)  = *(const float4*)&qs[k][tm * 8 + 4];
        *(float4*)(bb)     = *(const float4*)&ms[k][tn * 8];
        *(float4*)(bb + 4) = *(const float4*)&ms[k][tn * 8 + 4];
#pragma unroll
        for (int i = 0; i < 8; ++i)
#pragma unroll
          for (int j = 0; j < 8; ++j) acc[i][j] = fmaf(a[i], bb[j], acc[i][j]);
      }
    }
  }
#pragma unroll
  for (int i = 0; i < 8; ++i) {
    const int row = t0 + tm * 8 + i;
    const float inv = 1.0f / scale[(size_t)b * Sn + row];
    float* orow = out + (size_t)(b * Sn + row) * Cn + d0 + tn * 8;
    float4 o0 = *(const float4*)orow;
    float4 o1 = *(const float4*)(orow + 4);
    o0.x = (o0.x + acc[i][0]) * inv; o0.y = (o0.y + acc[i][1]) * inv;
    o0.z = (o0.z + acc[i][2]) * inv; o0.w = (o0.w + acc[i][3]) * inv;
    o1.x = (o1.x + acc[i][4]) * inv; o1.y = (o1.y + acc[i][5]) * inv;
    o1.z = (o1.z + acc[i][6]) * inv; o1.w = (o1.w + acc[i][7]) * inv;
    *(float4*)orow       = o0;
    *(float4*)(orow + 4) = o1;
  }
}

// ---------------- launch -----------------------------------------------------
extern "C" void kernel_launch(void* const* d_in, const int* in_sizes, int n_in,
                              void* d_out, int out_size, void* d_ws, size_t ws_size,
                              hipStream_t stream)
{
  const float* x  = (const float*)d_in[0];
  const float* Wq = (const float*)d_in[1];
  const float* Wk = (const float*)d_in[2];
  const float* Wv = (const float*)d_in[3];
  float* out = (float*)d_out;
  float* ws  = (float*)d_ws;

  float* PQ    = ws;                                   // 8.39M floats each
  float* PK    = PQ + (size_t)Bn * Sn * Cn;
  float* Vv    = PK + (size_t)Bn * Sn * Cn;
  float* A     = Vv + (size_t)Bn * Sn * Cn;            // B*NC*T*T = 2.10M
  float* zsum  = A + (size_t)Bn * NCn * Tn * Tn;       // 65536
  float* zpre  = zsum + (size_t)Bn * NCn * Cn;         // 65536
  float* scale = zpre + (size_t)Bn * NCn * Cn;         // 16384
  float* KV    = scale + (size_t)Bn * Sn;              // B*NC*C*C = 33.55M (134MB)
  (void)ws_size; (void)in_sizes; (void)n_in; (void)out_size;

  hipLaunchKernelGGL(k_proj, dim3(Cn / 128, (Bn * Sn) / 128, 3), dim3(256), 0, stream,
                     x, Wq, Wk, Wv, PQ, PK, Vv);
  hipLaunchKernelGGL(k_zsum, dim3(NCn, Bn), dim3(512), 0, stream, PK, zsum);
  hipLaunchKernelGGL(k_zpre, dim3(Bn), dim3(512), 0, stream, zsum, zpre);
  hipLaunchKernelGGL(k_gram, dim3(2, NCn, Bn), dim3(256), 0, stream, PQ, PK, A, scale);
  hipLaunchKernelGGL(k_scale, dim3(Sn / 4, Bn), dim3(256), 0, stream, PQ, zpre, scale);
  hipLaunchKernelGGL(k_av, dim3(Cn / 128, NCn, Bn), dim3(256), 0, stream, A, Vv, out);
  hipLaunchKernelGGL(k_kv, dim3(16, NCn, Bn), dim3(256), 0, stream, PK, Vv, KV);
  hipLaunchKernelGGL(k_prefix, dim3(256, Bn), dim3(256), 0, stream, KV);
  hipLaunchKernelGGL(k_inter, dim3(Cn / 128, NCn, Bn), dim3(256), 0, stream, PQ, KV, scale, out);
}

// Round 3
// 197.892 us; speedup vs baseline: 4.9075x; 3.4388x over previous
//
#include <hip/hip_runtime.h>

// LinearAttentionCell: chunked linear attention, bf16 MFMA version.
// All GEMM cores on matrix units (v_mfma_f32_16x16x32_bf16), fp32 accumulate.
// Layouts: PQ/PK row-major [t][c]; PKt/Vt transposed [c|d][t]; KVt [d][c]
// so every MFMA A/B operand reads k-contiguous rows (B^T GEMM pattern, m97).

constexpr int Bn  = 8;
constexpr int Sn  = 2048;
constexpr int Cn  = 512;
constexpr int Tn  = 128;
constexpr int NCn = 16;
constexpr float DKf = 0.04419417382415922f;     // 1/sqrt(512)

typedef __attribute__((ext_vector_type(8))) short bf16x8;
typedef __attribute__((ext_vector_type(4))) float f32x4;

__device__ __forceinline__ unsigned short f2bf(float f) {   // RNE
  unsigned u = __float_as_uint(f);
  u = (u + 0x7fffu + ((u >> 16) & 1u)) >> 16;
  return (unsigned short)u;
}
__device__ __forceinline__ float bf2f(unsigned short h) {
  return __uint_as_float(((unsigned)h) << 16);
}
__device__ __forceinline__ float phi_f(float u) {
  float s = u * DKf;
  return s > 0.0f ? s + 1.0f : __expf(s);       // elu(s)+1
}

// ---- stage a 128x32 bf16 tile global->LDS, XOR-swizzled (kslot ^= row&3) ----
__device__ __forceinline__ void stage128x32(const unsigned short* __restrict__ g,
                                            int ld, unsigned short* lds,
                                            int wid, int lane) {
#pragma unroll
  for (int cc = 0; cc < 2; ++cc) {
    const int row = cc * 64 + wid * 16 + (lane >> 2);
    const int ks  = (lane & 3) ^ (row & 3);
    const unsigned short* src = g + (size_t)row * ld + ks * 8;
    unsigned short* dst = lds + (size_t)(cc * 256 + wid * 64) * 8;  // wave-uniform
    __builtin_amdgcn_global_load_lds(
        (const __attribute__((address_space(1))) void*)src,
        (__attribute__((address_space(3))) void*)dst, 16, 0, 0);
  }
}

// ---- 128x128 output tile, 4 waves (2x2 of 64x64), K loop of 32-wide tiles ----
// Ag: row-major [128][lda] (rows = output M), Bg: row-major [128][ldb] (rows = output N).
__device__ __forceinline__ void mm_loop(const unsigned short* __restrict__ Ag, int lda,
                                        const unsigned short* __restrict__ Bg, int ldb,
                                        int nkt,
                                        unsigned short* Al, unsigned short* Bl,
                                        f32x4 acc[4][4]) {
  const int t = threadIdx.x, wid = t >> 6, lane = t & 63;
  const int wm = wid >> 1, wn = wid & 1;
  const int fr = lane & 15, kb = lane >> 4;
  for (int kt = 0; kt < nkt; ++kt) {
    __syncthreads();
    stage128x32(Ag + kt * 32, lda, Al, wid, lane);
    stage128x32(Bg + kt * 32, ldb, Bl, wid, lane);
    __syncthreads();
    bf16x8 af[4], bf[4];
#pragma unroll
    for (int m = 0; m < 4; ++m) {
      const int r = wm * 64 + m * 16 + fr;
      af[m] = *(const bf16x8*)&Al[r * 32 + ((kb ^ (r & 3)) << 3)];
    }
#pragma unroll
    for (int n = 0; n < 4; ++n) {
      const int r = wn * 64 + n * 16 + fr;
      bf[n] = *(const bf16x8*)&Bl[r * 32 + ((kb ^ (r & 3)) << 3)];
    }
#pragma unroll
    for (int m = 0; m < 4; ++m)
#pragma unroll
      for (int n = 0; n < 4; ++n)
        acc[m][n] = __builtin_amdgcn_mfma_f32_16x16x32_bf16(af[m], bf[n], acc[m][n], 0, 0, 0);
  }
}

// ---------------- casts ------------------------------------------------------
__global__ __launch_bounds__(256) void k_cast_x(const float* __restrict__ x,
                                                unsigned short* __restrict__ xb) {
  const size_t i8 = ((size_t)blockIdx.x * 256 + threadIdx.x) * 8;
  float4 a = *(const float4*)&x[i8];
  float4 b = *(const float4*)&x[i8 + 4];
  uint4 o;
  o.x = (unsigned)f2bf(a.x) | ((unsigned)f2bf(a.y) << 16);
  o.y = (unsigned)f2bf(a.z) | ((unsigned)f2bf(a.w) << 16);
  o.z = (unsigned)f2bf(b.x) | ((unsigned)f2bf(b.y) << 16);
  o.w = (unsigned)f2bf(b.z) | ((unsigned)f2bf(b.w) << 16);
  *(uint4*)&xb[i8] = o;
}

__global__ __launch_bounds__(256) void k_cast_w(const float* __restrict__ Wq,
                                                const float* __restrict__ Wk,
                                                const float* __restrict__ Wv,
                                                unsigned short* __restrict__ Wb) {
  const int z = blockIdx.y;
  const float* __restrict__ src = (z == 0) ? Wq : (z == 1 ? Wk : Wv);
  const size_t i8 = ((size_t)blockIdx.x * 256 + threadIdx.x) * 8;
  float4 a = *(const float4*)&src[i8];
  float4 b = *(const float4*)&src[i8 + 4];
  uint4 o;
  o.x = (unsigned)f2bf(a.x) | ((unsigned)f2bf(a.y) << 16);
  o.y = (unsigned)f2bf(a.z) | ((unsigned)f2bf(a.w) << 16);
  o.z = (unsigned)f2bf(b.x) | ((unsigned)f2bf(b.y) << 16);
  o.w = (unsigned)f2bf(b.z) | ((unsigned)f2bf(b.w) << 16);
  *(uint4*)&Wb[(size_t)z * Cn * Cn + i8] = o;
}

// ---------------- K1: projections (bf16 MFMA) --------------------------------
// out[m,n] = sum_k xb[m,k]*W[n,k]; z=0 -> PQ (phi), z=1 -> PK+PKt (phi), z=2 -> Vt.
__global__ __launch_bounds__(256) void k_proj(
    const unsigned short* __restrict__ xb, const unsigned short* __restrict__ Wb,
    unsigned short* __restrict__ PQ, unsigned short* __restrict__ PK,
    unsigned short* __restrict__ PKt, unsigned short* __restrict__ Vt)
{
  __shared__ unsigned short Al[128 * 32], Bl[128 * 32];
  const int z = blockIdx.z;
  const int m0 = blockIdx.y * 128, n0 = blockIdx.x * 128;
  f32x4 acc[4][4];
  const f32x4 zero = {0.f, 0.f, 0.f, 0.f};
#pragma unroll
  for (int m = 0; m < 4; ++m)
#pragma unroll
    for (int n = 0; n < 4; ++n) acc[m][n] = zero;

  mm_loop(xb + (size_t)m0 * Cn, Cn,
          Wb + (size_t)z * Cn * Cn + (size_t)n0 * Cn, Cn, Cn / 32, Al, Bl, acc);

  const int t = threadIdx.x, wid = t >> 6, lane = t & 63;
  const int wm = wid >> 1, wn = wid & 1;
#pragma unroll
  for (int m = 0; m < 4; ++m)
#pragma unroll
    for (int n = 0; n < 4; ++n) {
      const int row0 = m0 + wm * 64 + m * 16 + ((lane >> 4) << 2);
      const int col  = n0 + wn * 64 + n * 16 + (lane & 15);
      f32x4 v = acc[m][n];
      if (z == 0) {
#pragma unroll
        for (int j = 0; j < 4; ++j)
          PQ[(size_t)(row0 + j) * Cn + col] = f2bf(phi_f(v[j]));
      } else if (z == 1) {
        ushort4 p;
#pragma unroll
        for (int j = 0; j < 4; ++j) {
          unsigned short u = f2bf(phi_f(v[j]));
          PK[(size_t)(row0 + j) * Cn + col] = u;
          (&p.x)[j] = u;
        }
        const int b = row0 >> 11, tq = row0 & (Sn - 1);
        *(ushort4*)&PKt[((size_t)b * Cn + col) * Sn + tq] = p;
      } else {
        ushort4 p;
#pragma unroll
        for (int j = 0; j < 4; ++j) (&p.x)[j] = f2bf(v[j]);
        const int b = row0 >> 11, tq = row0 & (Sn - 1);
        *(ushort4*)&Vt[((size_t)b * Cn + col) * Sn + tq] = p;
      }
    }
}

// ---------------- K2a: A = tril(PQ_c PK_c^T) bf16, rowsum -> scale -----------
__global__ __launch_bounds__(256) void k_gram(
    const unsigned short* __restrict__ PQ, const unsigned short* __restrict__ PK,
    unsigned short* __restrict__ Abuf, float* __restrict__ scale)
{
  __shared__ unsigned short Al[128 * 32], Bl[128 * 32];
  __shared__ float rsmem[2][128];
  const int b = blockIdx.y, ch = blockIdx.x;
  const size_t base = ((size_t)b * Sn + ch * Tn) * Cn;
  f32x4 acc[4][4];
  const f32x4 zero = {0.f, 0.f, 0.f, 0.f};
#pragma unroll
  for (int m = 0; m < 4; ++m)
#pragma unroll
    for (int n = 0; n < 4; ++n) acc[m][n] = zero;

  mm_loop(PQ + base, Cn, PK + base, Cn, Cn / 32, Al, Bl, acc);

  const int t = threadIdx.x, wid = t >> 6, lane = t & 63;
  const int wm = wid >> 1, wn = wid & 1;
  float rsum[4][4];
#pragma unroll
  for (int m = 0; m < 4; ++m)
#pragma unroll
    for (int j = 0; j < 4; ++j) rsum[m][j] = 0.f;
#pragma unroll
  for (int m = 0; m < 4; ++m)
#pragma unroll
    for (int n = 0; n < 4; ++n) {
      f32x4 v = acc[m][n];
#pragma unroll
      for (int j = 0; j < 4; ++j) {
        const int row = wm * 64 + m * 16 + ((lane >> 4) << 2) + j;
        const int col = wn * 64 + n * 16 + (lane & 15);
        unsigned short u = (col <= row) ? f2bf(v[j]) : 0;
        Abuf[((size_t)(b * NCn + ch) * Tn + row) * Tn + col] = u;
        rsum[m][j] += bf2f(u);          // rowsum over the SAME rounded values
      }
    }
#pragma unroll
  for (int m = 0; m < 4; ++m)
#pragma unroll
    for (int j = 0; j < 4; ++j) {
      float r = rsum[m][j];
      r += __shfl_xor(r, 1); r += __shfl_xor(r, 2);
      r += __shfl_xor(r, 4); r += __shfl_xor(r, 8);
      if ((lane & 15) == 0)
        rsmem[wn][wm * 64 + m * 16 + ((lane >> 4) << 2) + j] = r;
    }
  __syncthreads();
  if (t < 128)
    scale[(size_t)b * Sn + ch * Tn + t] = rsmem[0][t] + rsmem[1][t];
}

// ---------------- K2b: intra = A @ V_c -> out (fp32, undivided) --------------
__global__ __launch_bounds__(256) void k_av(
    const unsigned short* __restrict__ Abuf, const unsigned short* __restrict__ Vt,
    float* __restrict__ out)
{
  __shared__ unsigned short Al[128 * 32], Bl[128 * 32];
  const int b = blockIdx.z, ch = blockIdx.y, d0 = blockIdx.x * 128;
  f32x4 acc[4][4];
  const f32x4 zero = {0.f, 0.f, 0.f, 0.f};
#pragma unroll
  for (int m = 0; m < 4; ++m)
#pragma unroll
    for (int n = 0; n < 4; ++n) acc[m][n] = zero;

  mm_loop(Abuf + (size_t)(b * NCn + ch) * Tn * Tn, Tn,
          Vt + ((size_t)b * Cn + d0) * Sn + ch * Tn, Sn, Tn / 32, Al, Bl, acc);

  const int t = threadIdx.x, wid = t >> 6, lane = t & 63;
  const int wm = wid >> 1, wn = wid & 1;
#pragma unroll
  for (int m = 0; m < 4; ++m)
#pragma unroll
    for (int n = 0; n < 4; ++n) {
      const int row0 = wm * 64 + m * 16 + ((lane >> 4) << 2);
      const int col  = d0 + wn * 64 + n * 16 + (lane & 15);
      f32x4 v = acc[m][n];
#pragma unroll
      for (int j = 0; j < 4; ++j)
        out[(size_t)(b * Sn + ch * Tn + row0 + j) * Cn + col] = v[j];
    }
}

// ---------------- Kz: z sums + scale finalize --------------------------------
__global__ __launch_bounds__(512) void k_zsum(const unsigned short* __restrict__ PK,
                                              float* __restrict__ zsum) {
  const int b = blockIdx.y, ch = blockIdx.x, c = threadIdx.x;
  const unsigned short* p = PK + ((size_t)b * Sn + ch * Tn) * Cn + c;
  float s = 0.f;
  for (int j = 0; j < Tn; ++j) s += bf2f(p[(size_t)j * Cn]);
  zsum[((size_t)b * NCn + ch) * Cn + c] = s;
}

__global__ __launch_bounds__(512) void k_zpre(const float* __restrict__ zsum,
                                              float* __restrict__ zpre) {
  const int b = blockIdx.x, c = threadIdx.x;
  float run = 0.f;
  for (int ch = 0; ch < NCn; ++ch) {
    zpre[((size_t)b * NCn + ch) * Cn + c] = run;
    run += zsum[((size_t)b * NCn + ch) * Cn + c];
  }
}

__global__ __launch_bounds__(256) void k_scale(const unsigned short* __restrict__ PQ,
                                               const float* __restrict__ zpre,
                                               float* __restrict__ scale) {
  const int b = blockIdx.y;
  const int w = threadIdx.x >> 6, lane = threadIdx.x & 63;
  const int row = blockIdx.x * 4 + w;
  const int ch = row >> 7;
  const unsigned short* pq = PQ + ((size_t)b * Sn + row) * Cn + lane * 8;
  const float* zp = zpre + ((size_t)b * NCn + ch) * Cn + lane * 8;
  uint4 q = *(const uint4*)pq;
  float4 z0 = *(const float4*)zp, z1 = *(const float4*)(zp + 4);
  float d = bf2f((unsigned short)(q.x & 0xffff)) * z0.x
          + bf2f((unsigned short)(q.x >> 16))    * z0.y
          + bf2f((unsigned short)(q.y & 0xffff)) * z0.z
          + bf2f((unsigned short)(q.y >> 16))    * z0.w
          + bf2f((unsigned short)(q.z & 0xffff)) * z1.x
          + bf2f((unsigned short)(q.z >> 16))    * z1.y
          + bf2f((unsigned short)(q.w & 0xffff)) * z1.z
          + bf2f((unsigned short)(q.w >> 16))    * z1.w;
#pragma unroll
  for (int off = 32; off > 0; off >>= 1) d += __shfl_xor(d, off);
  if (lane == 0) scale[(size_t)b * Sn + row] += d + 1e-5f;
}

// ---------------- K3a: KVt[d][c] = sum_j PK[t0+j][c] V[t0+j][d] --------------
__global__ __launch_bounds__(256) void k_kv(
    const unsigned short* __restrict__ PKt, const unsigned short* __restrict__ Vt,
    unsigned short* __restrict__ KVt)
{
  __shared__ unsigned short Al[128 * 32], Bl[128 * 32];
  const int b = blockIdx.z, ch = blockIdx.y;
  const int c0 = (blockIdx.x >> 2) * 128, d0 = (blockIdx.x & 3) * 128;
  f32x4 acc[4][4];
  const f32x4 zero = {0.f, 0.f, 0.f, 0.f};
#pragma unroll
  for (int m = 0; m < 4; ++m)
#pragma unroll
    for (int n = 0; n < 4; ++n) acc[m][n] = zero;

  mm_loop(PKt + ((size_t)b * Cn + c0) * Sn + ch * Tn, Sn,
          Vt  + ((size_t)b * Cn + d0) * Sn + ch * Tn, Sn, Tn / 32, Al, Bl, acc);

  const int t = threadIdx.x, wid = t >> 6, lane = t & 63;
  const int wm = wid >> 1, wn = wid & 1;
#pragma unroll
  for (int m = 0; m < 4; ++m)
#pragma unroll
    for (int n = 0; n < 4; ++n) {
      const int c_row = c0 + wm * 64 + m * 16 + ((lane >> 4) << 2);
      const int d     = d0 + wn * 64 + n * 16 + (lane & 15);
      f32x4 v = acc[m][n];
      ushort4 p;
#pragma unroll
      for (int j = 0; j < 4; ++j) (&p.x)[j] = f2bf(v[j]);
      *(ushort4*)&KVt[((size_t)(b * NCn + ch) * Cn + d) * Cn + c_row] = p;
    }
}

// ---------------- K3b: exclusive chunk prefix of KVt (in place, bf16) --------
__global__ __launch_bounds__(256) void k_prefix(unsigned short* __restrict__ KVt) {
  const int b = blockIdx.y;
  const size_t base = (size_t)b * NCn * Cn * Cn
                    + ((size_t)blockIdx.x * 256 + threadIdx.x) * 8;
  float run[8] = {0.f, 0.f, 0.f, 0.f, 0.f, 0.f, 0.f, 0.f};
  for (int ch = 0; ch < NCn; ++ch) {
    uint4* p = (uint4*)&KVt[base + (size_t)ch * Cn * Cn];
    uint4 cur = *p;
    float c[8];
    c[0] = bf2f((unsigned short)(cur.x & 0xffff)); c[1] = bf2f((unsigned short)(cur.x >> 16));
    c[2] = bf2f((unsigned short)(cur.y & 0xffff)); c[3] = bf2f((unsigned short)(cur.y >> 16));
    c[4] = bf2f((unsigned short)(cur.z & 0xffff)); c[5] = bf2f((unsigned short)(cur.z >> 16));
    c[6] = bf2f((unsigned short)(cur.w & 0xffff)); c[7] = bf2f((unsigned short)(cur.w >> 16));
    uint4 o;
    o.x = (unsigned)f2bf(run[0]) | ((unsigned)f2bf(run[1]) << 16);
    o.y = (unsigned)f2bf(run[2]) | ((unsigned)f2bf(run[3]) << 16);
    o.z = (unsigned)f2bf(run[4]) | ((unsigned)f2bf(run[5]) << 16);
    o.w = (unsigned)f2bf(run[6]) | ((unsigned)f2bf(run[7]) << 16);
    *p = o;
#pragma unroll
    for (int e = 0; e < 8; ++e) run[e] += c[e];
  }
}

// ---------------- K3c: out = (out + PQ_c @ Mpre_c) / scale -------------------
__global__ __launch_bounds__(256) void k_inter(
    const unsigned short* __restrict__ PQ, const unsigned short* __restrict__ KVt,
    const float* __restrict__ scale, float* __restrict__ out)
{
  __shared__ unsigned short Al[128 * 32], Bl[128 * 32];
  const int b = blockIdx.z, ch = blockIdx.y, d0 = blockIdx.x * 128;
  const int t0 = ch * Tn;
  f32x4 acc[4][4];
  const f32x4 zero = {0.f, 0.f, 0.f, 0.f};
#pragma unroll
  for (int m = 0; m < 4; ++m)
#pragma unroll
    for (int n = 0; n < 4; ++n) acc[m][n] = zero;

  if (ch > 0)
    mm_loop(PQ + ((size_t)b * Sn + t0) * Cn, Cn,
            KVt + ((size_t)(b * NCn + ch) * Cn + d0) * Cn, Cn, Cn / 32, Al, Bl, acc);

  const int t = threadIdx.x, wid = t >> 6, lane = t & 63;
  const int wm = wid >> 1, wn = wid & 1;
#pragma unroll
  for (int m = 0; m < 4; ++m)
#pragma unroll
    for (int n = 0; n < 4; ++n) {
      const int row0 = t0 + wm * 64 + m * 16 + ((lane >> 4) << 2);
      const int col  = d0 + wn * 64 + n * 16 + (lane & 15);
      f32x4 v = acc[m][n];
#pragma unroll
      for (int j = 0; j < 4; ++j) {
        const size_t sidx = (size_t)b * Sn + row0 + j;
        const float inv = 1.0f / scale[sidx];
        const size_t oidx = sidx * Cn + col;
        out[oidx] = (out[oidx] + v[j]) * inv;
      }
    }
}

// ---------------- launch -----------------------------------------------------
extern "C" void kernel_launch(void* const* d_in, const int* in_sizes, int n_in,
                              void* d_out, int out_size, void* d_ws, size_t ws_size,
                              hipStream_t stream)
{
  const float* x  = (const float*)d_in[0];
  const float* Wq = (const float*)d_in[1];
  const float* Wk = (const float*)d_in[2];
  const float* Wv = (const float*)d_in[3];
  float* out = (float*)d_out;

  unsigned short* xb   = (unsigned short*)d_ws;
  unsigned short* Wb   = xb   + (size_t)Bn * Sn * Cn;          // 8.39M
  unsigned short* PQ   = Wb   + (size_t)3 * Cn * Cn;           // 0.79M
  unsigned short* PK   = PQ   + (size_t)Bn * Sn * Cn;
  unsigned short* PKt  = PK   + (size_t)Bn * Sn * Cn;
  unsigned short* Vt   = PKt  + (size_t)Bn * Sn * Cn;
  unsigned short* Abuf = Vt   + (size_t)Bn * Sn * Cn;          // 2.10M
  unsigned short* KVt  = Abuf + (size_t)Bn * NCn * Tn * Tn;    // 33.55M
  float* scale = (float*)(KVt + (size_t)Bn * NCn * Cn * Cn);   // 16K
  float* zsum  = scale + (size_t)Bn * Sn;                      // 64K
  float* zpre  = zsum  + (size_t)Bn * NCn * Cn;                // 64K
  (void)ws_size; (void)in_sizes; (void)n_in; (void)out_size;

  hipLaunchKernelGGL(k_cast_x, dim3(4096), dim3(256), 0, stream, x, xb);
  hipLaunchKernelGGL(k_cast_w, dim3(128, 3), dim3(256), 0, stream, Wq, Wk, Wv, Wb);
  hipLaunchKernelGGL(k_proj, dim3(4, 128, 3), dim3(256), 0, stream, xb, Wb, PQ, PK, PKt, Vt);
  hipLaunchKernelGGL(k_zsum, dim3(NCn, Bn), dim3(512), 0, stream, PK, zsum);
  hipLaunchKernelGGL(k_zpre, dim3(Bn), dim3(512), 0, stream, zsum, zpre);
  hipLaunchKernelGGL(k_gram, dim3(NCn, Bn), dim3(256), 0, stream, PQ, PK, Abuf, scale);
  hipLaunchKernelGGL(k_scale, dim3(Sn / 4, Bn), dim3(256), 0, stream, PQ, zpre, scale);
  hipLaunchKernelGGL(k_av, dim3(4, NCn, Bn), dim3(256), 0, stream, Abuf, Vt, out);
  hipLaunchKernelGGL(k_kv, dim3(16, NCn, Bn), dim3(256), 0, stream, PKt, Vt, KVt);
  hipLaunchKernelGGL(k_prefix, dim3(128, Bn), dim3(256), 0, stream, KVt);
  hipLaunchKernelGGL(k_inter, dim3(4, NCn, Bn), dim3(256), 0, stream, PQ, KVt, scale, out);
}

// Round 4
// 179.828 us; speedup vs baseline: 5.4005x; 1.1005x over previous
//
#include <hip/hip_runtime.h>

// LinearAttentionCell: chunked linear attention, bf16 MFMA, traffic-minimized.
// R4: z-loop + XCD swizzle in proj; kv+prefix fused (fp32 running M, write
// exclusive prefix before accumulating); av+inter fused (single out write).

constexpr int Bn  = 8;
constexpr int Sn  = 2048;
constexpr int Cn  = 512;
constexpr int Tn  = 128;
constexpr int NCn = 16;
constexpr float DKf = 0.04419417382415922f;     // 1/sqrt(512)

typedef __attribute__((ext_vector_type(8))) short bf16x8;
typedef __attribute__((ext_vector_type(4))) float f32x4;

__device__ __forceinline__ unsigned short f2bf(float f) {   // RNE
  unsigned u = __float_as_uint(f);
  u = (u + 0x7fffu + ((u >> 16) & 1u)) >> 16;
  return (unsigned short)u;
}
__device__ __forceinline__ float bf2f(unsigned short h) {
  return __uint_as_float(((unsigned)h) << 16);
}
__device__ __forceinline__ float phi_f(float u) {
  float s = u * DKf;
  return s > 0.0f ? s + 1.0f : __expf(s);       // elu(s)+1
}

// ---- stage a 128x32 bf16 tile global->LDS, XOR-swizzled (kslot ^= row&3) ----
__device__ __forceinline__ void stage128x32(const unsigned short* __restrict__ g,
                                            int ld, unsigned short* lds,
                                            int wid, int lane) {
#pragma unroll
  for (int cc = 0; cc < 2; ++cc) {
    const int row = cc * 64 + wid * 16 + (lane >> 2);
    const int ks  = (lane & 3) ^ (row & 3);
    const unsigned short* src = g + (size_t)row * ld + ks * 8;
    unsigned short* dst = lds + (size_t)(cc * 256 + wid * 64) * 8;  // wave-uniform
    __builtin_amdgcn_global_load_lds(
        (const __attribute__((address_space(1))) void*)src,
        (__attribute__((address_space(3))) void*)dst, 16, 0, 0);
  }
}

// ---- 128x128 output tile, 4 waves (2x2 of 64x64), K loop of 32-wide tiles ----
// Ag: row-major [128][lda] (rows = output M), Bg: row-major [128][ldb] (rows = output N).
__device__ __forceinline__ void mm_loop(const unsigned short* __restrict__ Ag, int lda,
                                        const unsigned short* __restrict__ Bg, int ldb,
                                        int nkt,
                                        unsigned short* Al, unsigned short* Bl,
                                        f32x4 acc[4][4]) {
  const int t = threadIdx.x, wid = t >> 6, lane = t & 63;
  const int wm = wid >> 1, wn = wid & 1;
  const int fr = lane & 15, kb = lane >> 4;
  for (int kt = 0; kt < nkt; ++kt) {
    __syncthreads();
    stage128x32(Ag + kt * 32, lda, Al, wid, lane);
    stage128x32(Bg + kt * 32, ldb, Bl, wid, lane);
    __syncthreads();
    bf16x8 af[4], bf[4];
#pragma unroll
    for (int m = 0; m < 4; ++m) {
      const int r = wm * 64 + m * 16 + fr;
      af[m] = *(const bf16x8*)&Al[r * 32 + ((kb ^ (r & 3)) << 3)];
    }
#pragma unroll
    for (int n = 0; n < 4; ++n) {
      const int r = wn * 64 + n * 16 + fr;
      bf[n] = *(const bf16x8*)&Bl[r * 32 + ((kb ^ (r & 3)) << 3)];
    }
#pragma unroll
    for (int m = 0; m < 4; ++m)
#pragma unroll
      for (int n = 0; n < 4; ++n)
        acc[m][n] = __builtin_amdgcn_mfma_f32_16x16x32_bf16(af[m], bf[n], acc[m][n], 0, 0, 0);
  }
}

// ---------------- casts ------------------------------------------------------
__global__ __launch_bounds__(256) void k_cast_x(const float* __restrict__ x,
                                                unsigned short* __restrict__ xb) {
  const size_t i8 = ((size_t)blockIdx.x * 256 + threadIdx.x) * 8;
  float4 a = *(const float4*)&x[i8];
  float4 b = *(const float4*)&x[i8 + 4];
  uint4 o;
  o.x = (unsigned)f2bf(a.x) | ((unsigned)f2bf(a.y) << 16);
  o.y = (unsigned)f2bf(a.z) | ((unsigned)f2bf(a.w) << 16);
  o.z = (unsigned)f2bf(b.x) | ((unsigned)f2bf(b.y) << 16);
  o.w = (unsigned)f2bf(b.z) | ((unsigned)f2bf(b.w) << 16);
  *(uint4*)&xb[i8] = o;
}

__global__ __launch_bounds__(256) void k_cast_w(const float* __restrict__ Wq,
                                                const float* __restrict__ Wk,
                                                const float* __restrict__ Wv,
                                                unsigned short* __restrict__ Wb) {
  const int z = blockIdx.y;
  const float* __restrict__ src = (z == 0) ? Wq : (z == 1 ? Wk : Wv);
  const size_t i8 = ((size_t)blockIdx.x * 256 + threadIdx.x) * 8;
  float4 a = *(const float4*)&src[i8];
  float4 b = *(const float4*)&src[i8 + 4];
  uint4 o;
  o.x = (unsigned)f2bf(a.x) | ((unsigned)f2bf(a.y) << 16);
  o.y = (unsigned)f2bf(a.z) | ((unsigned)f2bf(a.w) << 16);
  o.z = (unsigned)f2bf(b.x) | ((unsigned)f2bf(b.y) << 16);
  o.w = (unsigned)f2bf(b.z) | ((unsigned)f2bf(b.w) << 16);
  *(uint4*)&Wb[(size_t)z * Cn * Cn + i8] = o;
}

// ---------------- K1: projections (bf16 MFMA, z-loop, XCD-swizzled) ----------
// 512 blocks; logical = (bid%8)*64 + bid/8 -> XCD k owns 16 contiguous m-slabs
// (2 MB xb + 1.5 MB Wb L2-resident); z in {q,k,v} looped inside for xb reuse.
__global__ __launch_bounds__(256) void k_proj(
    const unsigned short* __restrict__ xb, const unsigned short* __restrict__ Wb,
    unsigned short* __restrict__ PQ, unsigned short* __restrict__ PK,
    unsigned short* __restrict__ PKt, unsigned short* __restrict__ Vt)
{
  __shared__ unsigned short Al[128 * 32], Bl[128 * 32];
  const int bid = blockIdx.x;
  const int logical = (bid & 7) * 64 + (bid >> 3);
  const int n0 = (logical & 3) * 128;
  const int m0 = (logical >> 2) * 128;
  const int t = threadIdx.x, wid = t >> 6, lane = t & 63;
  const int wm = wid >> 1, wn = wid & 1;
  const f32x4 zero = {0.f, 0.f, 0.f, 0.f};

  for (int z = 0; z < 3; ++z) {
    f32x4 acc[4][4];
#pragma unroll
    for (int m = 0; m < 4; ++m)
#pragma unroll
      for (int n = 0; n < 4; ++n) acc[m][n] = zero;

    mm_loop(xb + (size_t)m0 * Cn, Cn,
            Wb + (size_t)z * Cn * Cn + (size_t)n0 * Cn, Cn, Cn / 32, Al, Bl, acc);

#pragma unroll
    for (int m = 0; m < 4; ++m)
#pragma unroll
      for (int n = 0; n < 4; ++n) {
        const int row0 = m0 + wm * 64 + m * 16 + ((lane >> 4) << 2);
        const int col  = n0 + wn * 64 + n * 16 + (lane & 15);
        f32x4 v = acc[m][n];
        if (z == 0) {
#pragma unroll
          for (int j = 0; j < 4; ++j)
            PQ[(size_t)(row0 + j) * Cn + col] = f2bf(phi_f(v[j]));
        } else if (z == 1) {
          ushort4 p;
#pragma unroll
          for (int j = 0; j < 4; ++j) {
            unsigned short u = f2bf(phi_f(v[j]));
            PK[(size_t)(row0 + j) * Cn + col] = u;
            (&p.x)[j] = u;
          }
          const int b = row0 >> 11, tq = row0 & (Sn - 1);
          *(ushort4*)&PKt[((size_t)b * Cn + col) * Sn + tq] = p;
        } else {
          ushort4 p;
#pragma unroll
          for (int j = 0; j < 4; ++j) (&p.x)[j] = f2bf(v[j]);
          const int b = row0 >> 11, tq = row0 & (Sn - 1);
          *(ushort4*)&Vt[((size_t)b * Cn + col) * Sn + tq] = p;
        }
      }
  }
}

// ---------------- K2a: A = tril(PQ_c PK_c^T) bf16, rowsum -> scale -----------
__global__ __launch_bounds__(256) void k_gram(
    const unsigned short* __restrict__ PQ, const unsigned short* __restrict__ PK,
    unsigned short* __restrict__ Abuf, float* __restrict__ scale)
{
  __shared__ unsigned short Al[128 * 32], Bl[128 * 32];
  __shared__ float rsmem[2][128];
  const int b = blockIdx.y, ch = blockIdx.x;
  const size_t base = ((size_t)b * Sn + ch * Tn) * Cn;
  f32x4 acc[4][4];
  const f32x4 zero = {0.f, 0.f, 0.f, 0.f};
#pragma unroll
  for (int m = 0; m < 4; ++m)
#pragma unroll
    for (int n = 0; n < 4; ++n) acc[m][n] = zero;

  mm_loop(PQ + base, Cn, PK + base, Cn, Cn / 32, Al, Bl, acc);

  const int t = threadIdx.x, wid = t >> 6, lane = t & 63;
  const int wm = wid >> 1, wn = wid & 1;
  float rsum[4][4];
#pragma unroll
  for (int m = 0; m < 4; ++m)
#pragma unroll
    for (int j = 0; j < 4; ++j) rsum[m][j] = 0.f;
#pragma unroll
  for (int m = 0; m < 4; ++m)
#pragma unroll
    for (int n = 0; n < 4; ++n) {
      f32x4 v = acc[m][n];
#pragma unroll
      for (int j = 0; j < 4; ++j) {
        const int row = wm * 64 + m * 16 + ((lane >> 4) << 2) + j;
        const int col = wn * 64 + n * 16 + (lane & 15);
        unsigned short u = (col <= row) ? f2bf(v[j]) : 0;
        Abuf[((size_t)(b * NCn + ch) * Tn + row) * Tn + col] = u;
        rsum[m][j] += bf2f(u);          // rowsum over the SAME rounded values
      }
    }
#pragma unroll
  for (int m = 0; m < 4; ++m)
#pragma unroll
    for (int j = 0; j < 4; ++j) {
      float r = rsum[m][j];
      r += __shfl_xor(r, 1); r += __shfl_xor(r, 2);
      r += __shfl_xor(r, 4); r += __shfl_xor(r, 8);
      if ((lane & 15) == 0)
        rsmem[wn][wm * 64 + m * 16 + ((lane >> 4) << 2) + j] = r;
    }
  __syncthreads();
  if (t < 128)
    scale[(size_t)b * Sn + ch * Tn + t] = rsmem[0][t] + rsmem[1][t];
}

// ---------------- Kz: z sums + scale finalize --------------------------------
__global__ __launch_bounds__(512) void k_zsum(const unsigned short* __restrict__ PK,
                                              float* __restrict__ zsum) {
  const int b = blockIdx.y, ch = blockIdx.x, c = threadIdx.x;
  const unsigned short* p = PK + ((size_t)b * Sn + ch * Tn) * Cn + c;
  float s = 0.f;
  for (int j = 0; j < Tn; ++j) s += bf2f(p[(size_t)j * Cn]);
  zsum[((size_t)b * NCn + ch) * Cn + c] = s;
}

__global__ __launch_bounds__(512) void k_zpre(const float* __restrict__ zsum,
                                              float* __restrict__ zpre) {
  const int b = blockIdx.x, c = threadIdx.x;
  float run = 0.f;
  for (int ch = 0; ch < NCn; ++ch) {
    zpre[((size_t)b * NCn + ch) * Cn + c] = run;
    run += zsum[((size_t)b * NCn + ch) * Cn + c];
  }
}

__global__ __launch_bounds__(256) void k_scale(const unsigned short* __restrict__ PQ,
                                               const float* __restrict__ zpre,
                                               float* __restrict__ scale) {
  const int b = blockIdx.y;
  const int w = threadIdx.x >> 6, lane = threadIdx.x & 63;
  const int row = blockIdx.x * 4 + w;
  const int ch = row >> 7;
  const unsigned short* pq = PQ + ((size_t)b * Sn + row) * Cn + lane * 8;
  const float* zp = zpre + ((size_t)b * NCn + ch) * Cn + lane * 8;
  uint4 q = *(const uint4*)pq;
  float4 z0 = *(const float4*)zp, z1 = *(const float4*)(zp + 4);
  float d = bf2f((unsigned short)(q.x & 0xffff)) * z0.x
          + bf2f((unsigned short)(q.x >> 16))    * z0.y
          + bf2f((unsigned short)(q.y & 0xffff)) * z0.z
          + bf2f((unsigned short)(q.y >> 16))    * z0.w
          + bf2f((unsigned short)(q.z & 0xffff)) * z1.x
          + bf2f((unsigned short)(q.z >> 16))    * z1.y
          + bf2f((unsigned short)(q.w & 0xffff)) * z1.z
          + bf2f((unsigned short)(q.w >> 16))    * z1.w;
#pragma unroll
  for (int off = 32; off > 0; off >>= 1) d += __shfl_xor(d, off);
  if (lane == 0) scale[(size_t)b * Sn + row] += d + 1e-5f;
}

// ---------------- K3a: fused KV + exclusive prefix ---------------------------
// 512 blocks, XCD-swizzled: XCD k owns batch k (PKt/Vt slabs L2-resident).
// Block owns a 64(c) x 64(d) tile of M; walks chunks serially: writes the
// fp32 running prefix (as bf16 Mpre[ch]) BEFORE mfma-accumulating chunk ch.
__global__ __launch_bounds__(256) void k_kvp(
    const unsigned short* __restrict__ PKt, const unsigned short* __restrict__ Vt,
    unsigned short* __restrict__ Mpre)
{
  __shared__ unsigned short Al[64 * 32], Bl[64 * 32];
  const int bid = blockIdx.x;
  const int logical = (bid & 7) * 64 + (bid >> 3);
  const int d0 = (logical & 7) * 64;
  const int c0 = ((logical >> 3) & 7) * 64;
  const int b  = logical >> 6;
  const int t = threadIdx.x, wid = t >> 6, lane = t & 63;
  const int wm = wid >> 1, wn = wid & 1;
  const int fr = lane & 15, kb = lane >> 4;
  f32x4 acc[2][2];
  const f32x4 zero = {0.f, 0.f, 0.f, 0.f};
#pragma unroll
  for (int m = 0; m < 2; ++m)
#pragma unroll
    for (int n = 0; n < 2; ++n) acc[m][n] = zero;
  const unsigned short* Ag = PKt + ((size_t)b * Cn + c0) * Sn;
  const unsigned short* Bg = Vt  + ((size_t)b * Cn + d0) * Sn;
  const int srow = wid * 16 + (lane >> 2);
  const int sks  = ((lane & 3) ^ (srow & 3)) * 8;
  for (int ch = 0; ch < NCn; ++ch) {
    if (ch > 0) {   // Mpre[ch] = sum of chunks < ch (Mpre[0] is never read)
#pragma unroll
      for (int m = 0; m < 2; ++m)
#pragma unroll
        for (int n = 0; n < 2; ++n) {
          const int c_row = c0 + wm * 32 + m * 16 + ((lane >> 4) << 2);
          const int d     = d0 + wn * 32 + n * 16 + fr;
          ushort4 p;
#pragma unroll
          for (int j = 0; j < 4; ++j) (&p.x)[j] = f2bf(acc[m][n][j]);
          *(ushort4*)&Mpre[((size_t)(b * NCn + ch) * Cn + d) * Cn + c_row] = p;
        }
    }
    for (int kt = 0; kt < 4; ++kt) {
      __syncthreads();
      __builtin_amdgcn_global_load_lds(
          (const __attribute__((address_space(1))) void*)
              (Ag + (size_t)srow * Sn + ch * Tn + kt * 32 + sks),
          (__attribute__((address_space(3))) void*)(Al + wid * 16 * 32), 16, 0, 0);
      __builtin_amdgcn_global_load_lds(
          (const __attribute__((address_space(1))) void*)
              (Bg + (size_t)srow * Sn + ch * Tn + kt * 32 + sks),
          (__attribute__((address_space(3))) void*)(Bl + wid * 16 * 32), 16, 0, 0);
      __syncthreads();
      bf16x8 af[2], bf[2];
#pragma unroll
      for (int m = 0; m < 2; ++m) {
        const int r = wm * 32 + m * 16 + fr;
        af[m] = *(const bf16x8*)&Al[r * 32 + ((kb ^ (r & 3)) << 3)];
      }
#pragma unroll
      for (int n = 0; n < 2; ++n) {
        const int r = wn * 32 + n * 16 + fr;
        bf[n] = *(const bf16x8*)&Bl[r * 32 + ((kb ^ (r & 3)) << 3)];
      }
#pragma unroll
      for (int m = 0; m < 2; ++m)
#pragma unroll
        for (int n = 0; n < 2; ++n)
          acc[m][n] = __builtin_amdgcn_mfma_f32_16x16x32_bf16(af[m], bf[n], acc[m][n], 0, 0, 0);
    }
  }
}

// ---------------- K3b: out = (A@V_c + PQ_c@Mpre_c) / scale (single write) ----
// 512 blocks, XCD-swizzled: XCD k owns batch k.
__global__ __launch_bounds__(256) void k_avinter(
    const unsigned short* __restrict__ Abuf, const unsigned short* __restrict__ Vt,
    const unsigned short* __restrict__ PQ, const unsigned short* __restrict__ Mpre,
    const float* __restrict__ scale, float* __restrict__ out)
{
  __shared__ unsigned short Al[128 * 32], Bl[128 * 32];
  const int bid = blockIdx.x;
  const int logical = (bid & 7) * 64 + (bid >> 3);
  const int d0 = (logical & 3) * 128;
  const int ch = (logical >> 2) & 15;
  const int b  = logical >> 6;
  const int t0 = ch * Tn;
  f32x4 acc[4][4];
  const f32x4 zero = {0.f, 0.f, 0.f, 0.f};
#pragma unroll
  for (int m = 0; m < 4; ++m)
#pragma unroll
    for (int n = 0; n < 4; ++n) acc[m][n] = zero;

  // intra: A (128x128) @ V_c  (K = 128)
  mm_loop(Abuf + (size_t)(b * NCn + ch) * Tn * Tn, Tn,
          Vt + ((size_t)b * Cn + d0) * Sn + t0, Sn, Tn / 32, Al, Bl, acc);
  // inter: PQ_c @ Mpre_c  (K = 512)
  if (ch > 0)
    mm_loop(PQ + ((size_t)b * Sn + t0) * Cn, Cn,
            Mpre + ((size_t)(b * NCn + ch) * Cn + d0) * Cn, Cn, Cn / 32, Al, Bl, acc);

  const int t = threadIdx.x, wid = t >> 6, lane = t & 63;
  const int wm = wid >> 1, wn = wid & 1;
#pragma unroll
  for (int m = 0; m < 4; ++m)
#pragma unroll
    for (int n = 0; n < 4; ++n) {
      const int row0 = t0 + wm * 64 + m * 16 + ((lane >> 4) << 2);
      const int col  = d0 + wn * 64 + n * 16 + (lane & 15);
      f32x4 v = acc[m][n];
#pragma unroll
      for (int j = 0; j < 4; ++j) {
        const size_t sidx = (size_t)b * Sn + row0 + j;
        out[sidx * Cn + col] = v[j] / scale[sidx];
      }
    }
}

// ---------------- launch -----------------------------------------------------
extern "C" void kernel_launch(void* const* d_in, const int* in_sizes, int n_in,
                              void* d_out, int out_size, void* d_ws, size_t ws_size,
                              hipStream_t stream)
{
  const float* x  = (const float*)d_in[0];
  const float* Wq = (const float*)d_in[1];
  const float* Wk = (const float*)d_in[2];
  const float* Wv = (const float*)d_in[3];
  float* out = (float*)d_out;

  unsigned short* xb   = (unsigned short*)d_ws;
  unsigned short* Wb   = xb   + (size_t)Bn * Sn * Cn;          // 8.39M
  unsigned short* PQ   = Wb   + (size_t)3 * Cn * Cn;           // 0.79M
  unsigned short* PK   = PQ   + (size_t)Bn * Sn * Cn;
  unsigned short* PKt  = PK   + (size_t)Bn * Sn * Cn;
  unsigned short* Vt   = PKt  + (size_t)Bn * Sn * Cn;
  unsigned short* Abuf = Vt   + (size_t)Bn * Sn * Cn;          // 2.10M
  unsigned short* Mpre = Abuf + (size_t)Bn * NCn * Tn * Tn;    // 33.55M
  float* scale = (float*)(Mpre + (size_t)Bn * NCn * Cn * Cn);  // 16K
  float* zsum  = scale + (size_t)Bn * Sn;                      // 64K
  float* zpre  = zsum  + (size_t)Bn * NCn * Cn;                // 64K
  (void)ws_size; (void)in_sizes; (void)n_in; (void)out_size;

  hipLaunchKernelGGL(k_cast_x, dim3(4096), dim3(256), 0, stream, x, xb);
  hipLaunchKernelGGL(k_cast_w, dim3(128, 3), dim3(256), 0, stream, Wq, Wk, Wv, Wb);
  hipLaunchKernelGGL(k_proj, dim3(512), dim3(256), 0, stream, xb, Wb, PQ, PK, PKt, Vt);
  hipLaunchKernelGGL(k_zsum, dim3(NCn, Bn), dim3(512), 0, stream, PK, zsum);
  hipLaunchKernelGGL(k_zpre, dim3(Bn), dim3(512), 0, stream, zsum, zpre);
  hipLaunchKernelGGL(k_gram, dim3(NCn, Bn), dim3(256), 0, stream, PQ, PK, Abuf, scale);
  hipLaunchKernelGGL(k_scale, dim3(Sn / 4, Bn), dim3(256), 0, stream, PQ, zpre, scale);
  hipLaunchKernelGGL(k_kvp, dim3(512), dim3(256), 0, stream, PKt, Vt, Mpre);
  hipLaunchKernelGGL(k_avinter, dim3(512), dim3(256), 0, stream, Abuf, Vt, PQ, Mpre, scale, out);
}

// Round 5
// 139.799 us; speedup vs baseline: 6.9469x; 1.2863x over previous
//
#include <hip/hip_runtime.h>

// LinearAttentionCell: chunked linear attention, bf16 MFMA, traffic-minimized.
// R5: proj back to 1536 blocks (z in grid) with XCD-local m-slabs; zsum fused
// into proj's z==1 epilogue; 2-way LDS swizzle ((r>>1)&3); kvp BK=128.

constexpr int Bn  = 8;
constexpr int Sn  = 2048;
constexpr int Cn  = 512;
constexpr int Tn  = 128;
constexpr int NCn = 16;
constexpr float DKf = 0.04419417382415922f;     // 1/sqrt(512)

typedef __attribute__((ext_vector_type(8))) short bf16x8;
typedef __attribute__((ext_vector_type(4))) float f32x4;

__device__ __forceinline__ unsigned short f2bf(float f) {   // RNE
  unsigned u = __float_as_uint(f);
  u = (u + 0x7fffu + ((u >> 16) & 1u)) >> 16;
  return (unsigned short)u;
}
__device__ __forceinline__ float bf2f(unsigned short h) {
  return __uint_as_float(((unsigned)h) << 16);
}
__device__ __forceinline__ float phi_f(float u) {
  float s = u * DKf;
  return s > 0.0f ? s + 1.0f : __expf(s);       // elu(s)+1
}

// ---- stage a 128x32 bf16 tile global->LDS, swizzle kslot ^= (row>>1)&3 ------
__device__ __forceinline__ void stage128x32(const unsigned short* __restrict__ g,
                                            int ld, unsigned short* lds,
                                            int wid, int lane) {
#pragma unroll
  for (int cc = 0; cc < 2; ++cc) {
    const int row = cc * 64 + wid * 16 + (lane >> 2);
    const int ks  = (lane & 3) ^ ((row >> 1) & 3);
    const unsigned short* src = g + (size_t)row * ld + ks * 8;
    unsigned short* dst = lds + (size_t)(cc * 256 + wid * 64) * 8;  // wave-uniform
    __builtin_amdgcn_global_load_lds(
        (const __attribute__((address_space(1))) void*)src,
        (__attribute__((address_space(3))) void*)dst, 16, 0, 0);
  }
}

// ---- 128x128 output tile, 4 waves (2x2 of 64x64), K loop of 32-wide tiles ----
__device__ __forceinline__ void mm_loop(const unsigned short* __restrict__ Ag, int lda,
                                        const unsigned short* __restrict__ Bg, int ldb,
                                        int nkt,
                                        unsigned short* Al, unsigned short* Bl,
                                        f32x4 acc[4][4]) {
  const int t = threadIdx.x, wid = t >> 6, lane = t & 63;
  const int wm = wid >> 1, wn = wid & 1;
  const int fr = lane & 15, kb = lane >> 4;
  for (int kt = 0; kt < nkt; ++kt) {
    __syncthreads();
    stage128x32(Ag + kt * 32, lda, Al, wid, lane);
    stage128x32(Bg + kt * 32, ldb, Bl, wid, lane);
    __syncthreads();
    bf16x8 af[4], bf[4];
#pragma unroll
    for (int m = 0; m < 4; ++m) {
      const int r = wm * 64 + m * 16 + fr;
      af[m] = *(const bf16x8*)&Al[r * 32 + ((kb ^ ((r >> 1) & 3)) << 3)];
    }
#pragma unroll
    for (int n = 0; n < 4; ++n) {
      const int r = wn * 64 + n * 16 + fr;
      bf[n] = *(const bf16x8*)&Bl[r * 32 + ((kb ^ ((r >> 1) & 3)) << 3)];
    }
#pragma unroll
    for (int m = 0; m < 4; ++m)
#pragma unroll
      for (int n = 0; n < 4; ++n)
        acc[m][n] = __builtin_amdgcn_mfma_f32_16x16x32_bf16(af[m], bf[n], acc[m][n], 0, 0, 0);
  }
}

// ---------------- casts ------------------------------------------------------
__global__ __launch_bounds__(256) void k_cast_x(const float* __restrict__ x,
                                                unsigned short* __restrict__ xb) {
  const size_t i8 = ((size_t)blockIdx.x * 256 + threadIdx.x) * 8;
  float4 a = *(const float4*)&x[i8];
  float4 b = *(const float4*)&x[i8 + 4];
  uint4 o;
  o.x = (unsigned)f2bf(a.x) | ((unsigned)f2bf(a.y) << 16);
  o.y = (unsigned)f2bf(a.z) | ((unsigned)f2bf(a.w) << 16);
  o.z = (unsigned)f2bf(b.x) | ((unsigned)f2bf(b.y) << 16);
  o.w = (unsigned)f2bf(b.z) | ((unsigned)f2bf(b.w) << 16);
  *(uint4*)&xb[i8] = o;
}

__global__ __launch_bounds__(256) void k_cast_w(const float* __restrict__ Wq,
                                                const float* __restrict__ Wk,
                                                const float* __restrict__ Wv,
                                                unsigned short* __restrict__ Wb) {
  const int z = blockIdx.y;
  const float* __restrict__ src = (z == 0) ? Wq : (z == 1 ? Wk : Wv);
  const size_t i8 = ((size_t)blockIdx.x * 256 + threadIdx.x) * 8;
  float4 a = *(const float4*)&src[i8];
  float4 b = *(const float4*)&src[i8 + 4];
  uint4 o;
  o.x = (unsigned)f2bf(a.x) | ((unsigned)f2bf(a.y) << 16);
  o.y = (unsigned)f2bf(a.z) | ((unsigned)f2bf(a.w) << 16);
  o.z = (unsigned)f2bf(b.x) | ((unsigned)f2bf(b.y) << 16);
  o.w = (unsigned)f2bf(b.z) | ((unsigned)f2bf(b.w) << 16);
  *(uint4*)&Wb[(size_t)z * Cn * Cn + i8] = o;
}

// ---------------- K1: projections (bf16 MFMA, XCD-local m-slabs) -------------
// 1536 blocks: xcd = bid&7 owns 16 contiguous m-slabs x 4 n x 3 z
// (2 MB xb + 1.5 MB Wb per-XCD L2-resident). z==1 blocks also emit zsum.
__global__ __launch_bounds__(256) void k_proj(
    const unsigned short* __restrict__ xb, const unsigned short* __restrict__ Wb,
    unsigned short* __restrict__ PQ, unsigned short* __restrict__ PK,
    unsigned short* __restrict__ PKt, unsigned short* __restrict__ Vt,
    float* __restrict__ zsum)
{
  __shared__ unsigned short Al[128 * 32], Bl[128 * 32];
  __shared__ float zbuf[2][128];
  const int bid = blockIdx.x;
  const int xcd = bid & 7, idx = bid >> 3;            // idx in 0..191
  const int n = idx & 3, z = (idx >> 2) % 3, mloc = idx / 12;
  const int n0 = n * 128, m0 = (xcd * 16 + mloc) * 128;
  const int t = threadIdx.x, wid = t >> 6, lane = t & 63;
  const int wm = wid >> 1, wn = wid & 1;
  f32x4 acc[4][4];
  const f32x4 zero = {0.f, 0.f, 0.f, 0.f};
#pragma unroll
  for (int m = 0; m < 4; ++m)
#pragma unroll
    for (int nn = 0; nn < 4; ++nn) acc[m][nn] = zero;

  mm_loop(xb + (size_t)m0 * Cn, Cn,
          Wb + (size_t)z * Cn * Cn + (size_t)n0 * Cn, Cn, Cn / 32, Al, Bl, acc);

  float ps[4] = {0.f, 0.f, 0.f, 0.f};
#pragma unroll
  for (int m = 0; m < 4; ++m)
#pragma unroll
    for (int nn = 0; nn < 4; ++nn) {
      const int row0 = m0 + wm * 64 + m * 16 + ((lane >> 4) << 2);
      const int col  = n0 + wn * 64 + nn * 16 + (lane & 15);
      f32x4 v = acc[m][nn];
      if (z == 0) {
#pragma unroll
        for (int j = 0; j < 4; ++j)
          PQ[(size_t)(row0 + j) * Cn + col] = f2bf(phi_f(v[j]));
      } else if (z == 1) {
        ushort4 p;
#pragma unroll
        for (int j = 0; j < 4; ++j) {
          unsigned short u = f2bf(phi_f(v[j]));
          PK[(size_t)(row0 + j) * Cn + col] = u;
          (&p.x)[j] = u;
          ps[nn] += bf2f(u);
        }
        const int b = row0 >> 11, tq = row0 & (Sn - 1);
        *(ushort4*)&PKt[((size_t)b * Cn + col) * Sn + tq] = p;
      } else {
        ushort4 p;
#pragma unroll
        for (int j = 0; j < 4; ++j) (&p.x)[j] = f2bf(v[j]);
        const int b = row0 >> 11, tq = row0 & (Sn - 1);
        *(ushort4*)&Vt[((size_t)b * Cn + col) * Sn + tq] = p;
      }
    }

  if (z == 1) {   // block covers one (b, chunk) x cols n0..n0+127 completely
#pragma unroll
    for (int nn = 0; nn < 4; ++nn) {
      float v = ps[nn];
      v += __shfl_xor(v, 16); v += __shfl_xor(v, 32);   // reduce over kb
      if (lane < 16) zbuf[wm][wn * 64 + nn * 16 + lane] = v;
    }
    __syncthreads();
    if (t < 128) {
      const int b = m0 >> 11, ch = (m0 >> 7) & 15;
      zsum[((size_t)b * NCn + ch) * Cn + n0 + t] = zbuf[0][t] + zbuf[1][t];
    }
  }
}

// ---------------- K2a: A = tril(PQ_c PK_c^T) bf16, rowsum -> scale -----------
__global__ __launch_bounds__(256) void k_gram(
    const unsigned short* __restrict__ PQ, const unsigned short* __restrict__ PK,
    unsigned short* __restrict__ Abuf, float* __restrict__ scale)
{
  __shared__ unsigned short Al[128 * 32], Bl[128 * 32];
  __shared__ float rsmem[2][128];
  const int b = blockIdx.y, ch = blockIdx.x;
  const size_t base = ((size_t)b * Sn + ch * Tn) * Cn;
  f32x4 acc[4][4];
  const f32x4 zero = {0.f, 0.f, 0.f, 0.f};
#pragma unroll
  for (int m = 0; m < 4; ++m)
#pragma unroll
    for (int n = 0; n < 4; ++n) acc[m][n] = zero;

  mm_loop(PQ + base, Cn, PK + base, Cn, Cn / 32, Al, Bl, acc);

  const int t = threadIdx.x, wid = t >> 6, lane = t & 63;
  const int wm = wid >> 1, wn = wid & 1;
  float rsum[4][4];
#pragma unroll
  for (int m = 0; m < 4; ++m)
#pragma unroll
    for (int j = 0; j < 4; ++j) rsum[m][j] = 0.f;
#pragma unroll
  for (int m = 0; m < 4; ++m)
#pragma unroll
    for (int n = 0; n < 4; ++n) {
      f32x4 v = acc[m][n];
#pragma unroll
      for (int j = 0; j < 4; ++j) {
        const int row = wm * 64 + m * 16 + ((lane >> 4) << 2) + j;
        const int col = wn * 64 + n * 16 + (lane & 15);
        unsigned short u = (col <= row) ? f2bf(v[j]) : 0;
        Abuf[((size_t)(b * NCn + ch) * Tn + row) * Tn + col] = u;
        rsum[m][j] += bf2f(u);          // rowsum over the SAME rounded values
      }
    }
#pragma unroll
  for (int m = 0; m < 4; ++m)
#pragma unroll
    for (int j = 0; j < 4; ++j) {
      float r = rsum[m][j];
      r += __shfl_xor(r, 1); r += __shfl_xor(r, 2);
      r += __shfl_xor(r, 4); r += __shfl_xor(r, 8);
      if ((lane & 15) == 0)
        rsmem[wn][wm * 64 + m * 16 + ((lane >> 4) << 2) + j] = r;
    }
  __syncthreads();
  if (t < 128)
    scale[(size_t)b * Sn + ch * Tn + t] = rsmem[0][t] + rsmem[1][t];
}

// ---------------- Kz: zpre + scale finalize ----------------------------------
__global__ __launch_bounds__(512) void k_zpre(const float* __restrict__ zsum,
                                              float* __restrict__ zpre) {
  const int b = blockIdx.x, c = threadIdx.x;
  float run = 0.f;
  for (int ch = 0; ch < NCn; ++ch) {
    zpre[((size_t)b * NCn + ch) * Cn + c] = run;
    run += zsum[((size_t)b * NCn + ch) * Cn + c];
  }
}

__global__ __launch_bounds__(256) void k_scale(const unsigned short* __restrict__ PQ,
                                               const float* __restrict__ zpre,
                                               float* __restrict__ scale) {
  const int b = blockIdx.y;
  const int w = threadIdx.x >> 6, lane = threadIdx.x & 63;
  const int row = blockIdx.x * 4 + w;
  const int ch = row >> 7;
  const unsigned short* pq = PQ + ((size_t)b * Sn + row) * Cn + lane * 8;
  const float* zp = zpre + ((size_t)b * NCn + ch) * Cn + lane * 8;
  uint4 q = *(const uint4*)pq;
  float4 z0 = *(const float4*)zp, z1 = *(const float4*)(zp + 4);
  float d = bf2f((unsigned short)(q.x & 0xffff)) * z0.x
          + bf2f((unsigned short)(q.x >> 16))    * z0.y
          + bf2f((unsigned short)(q.y & 0xffff)) * z0.z
          + bf2f((unsigned short)(q.y >> 16))    * z0.w
          + bf2f((unsigned short)(q.z & 0xffff)) * z1.x
          + bf2f((unsigned short)(q.z >> 16))    * z1.y
          + bf2f((unsigned short)(q.w & 0xffff)) * z1.z
          + bf2f((unsigned short)(q.w >> 16))    * z1.w;
#pragma unroll
  for (int off = 32; off > 0; off >>= 1) d += __shfl_xor(d, off);
  if (lane == 0) scale[(size_t)b * Sn + row] += d + 1e-5f;
}

// ---- stage a 64x128 bf16 tile global->LDS, swizzle slot ^= row&7 ------------
__device__ __forceinline__ void stage64x128(const unsigned short* __restrict__ g,
                                            int ld, unsigned short* lds,
                                            int wid, int lane) {
#pragma unroll
  for (int i = 0; i < 4; ++i) {
    const int row = wid * 16 + i * 4 + (lane >> 4);
    const int s   = (lane & 15) ^ (row & 7);
    const unsigned short* src = g + (size_t)row * ld + s * 8;
    unsigned short* dst = lds + (size_t)(wid * 16 + i * 4) * 128;   // wave-uniform
    __builtin_amdgcn_global_load_lds(
        (const __attribute__((address_space(1))) void*)src,
        (__attribute__((address_space(3))) void*)dst, 16, 0, 0);
  }
}

// ---------------- K3a: fused KV + exclusive prefix (BK=128) ------------------
// 512 blocks; XCD k owns batch k (PKt/Vt ~4 MB L2). Block owns a 64(c)x64(d)
// tile of M; per chunk: write running prefix (bf16) then accumulate chunk KV.
__global__ __launch_bounds__(256) void k_kvp(
    const unsigned short* __restrict__ PKt, const unsigned short* __restrict__ Vt,
    unsigned short* __restrict__ Mpre)
{
  __shared__ unsigned short Al[64 * 128], Bl[64 * 128];
  const int bid = blockIdx.x;
  const int b = bid & 7, idx = bid >> 3;
  const int d0 = (idx & 7) * 64, c0 = (idx >> 3) * 64;
  const int t = threadIdx.x, wid = t >> 6, lane = t & 63;
  const int wm = wid >> 1, wn = wid & 1;
  const int fr = lane & 15, kb = lane >> 4;
  f32x4 acc[2][2];
  const f32x4 zero = {0.f, 0.f, 0.f, 0.f};
#pragma unroll
  for (int m = 0; m < 2; ++m)
#pragma unroll
    for (int n = 0; n < 2; ++n) acc[m][n] = zero;
  const unsigned short* Ag = PKt + ((size_t)b * Cn + c0) * Sn;
  const unsigned short* Bg = Vt  + ((size_t)b * Cn + d0) * Sn;
  for (int ch = 0; ch < NCn; ++ch) {
    if (ch > 0) {   // Mpre[ch] = sum of chunks < ch (Mpre[0] never read)
#pragma unroll
      for (int m = 0; m < 2; ++m)
#pragma unroll
        for (int n = 0; n < 2; ++n) {
          const int c_row = c0 + wm * 32 + m * 16 + (kb << 2);
          const int d     = d0 + wn * 32 + n * 16 + fr;
          ushort4 p;
#pragma unroll
          for (int j = 0; j < 4; ++j) (&p.x)[j] = f2bf(acc[m][n][j]);
          *(ushort4*)&Mpre[((size_t)(b * NCn + ch) * Cn + d) * Cn + c_row] = p;
        }
    }
    __syncthreads();
    stage64x128(Ag + ch * Tn, Sn, Al, wid, lane);
    stage64x128(Bg + ch * Tn, Sn, Bl, wid, lane);
    __syncthreads();
#pragma unroll
    for (int kt = 0; kt < 4; ++kt) {
      bf16x8 af[2], bf[2];
#pragma unroll
      for (int m = 0; m < 2; ++m) {
        const int r = wm * 32 + m * 16 + fr;
        af[m] = *(const bf16x8*)&Al[r * 128 + (((kt * 4 + kb) ^ (r & 7)) << 3)];
      }
#pragma unroll
      for (int n = 0; n < 2; ++n) {
        const int r = wn * 32 + n * 16 + fr;
        bf[n] = *(const bf16x8*)&Bl[r * 128 + (((kt * 4 + kb) ^ (r & 7)) << 3)];
      }
#pragma unroll
      for (int m = 0; m < 2; ++m)
#pragma unroll
        for (int n = 0; n < 2; ++n)
          acc[m][n] = __builtin_amdgcn_mfma_f32_16x16x32_bf16(af[m], bf[n], acc[m][n], 0, 0, 0);
    }
  }
}

// ---------------- K3b: out = (A@V_c + PQ_c@Mpre_c) / scale (single write) ----
__global__ __launch_bounds__(256) void k_avinter(
    const unsigned short* __restrict__ Abuf, const unsigned short* __restrict__ Vt,
    const unsigned short* __restrict__ PQ, const unsigned short* __restrict__ Mpre,
    const float* __restrict__ scale, float* __restrict__ out)
{
  __shared__ unsigned short Al[128 * 32], Bl[128 * 32];
  const int bid = blockIdx.x;
  const int logical = (bid & 7) * 64 + (bid >> 3);
  const int d0 = (logical & 3) * 128;
  const int ch = (logical >> 2) & 15;
  const int b  = logical >> 6;
  const int t0 = ch * Tn;
  f32x4 acc[4][4];
  const f32x4 zero = {0.f, 0.f, 0.f, 0.f};
#pragma unroll
  for (int m = 0; m < 4; ++m)
#pragma unroll
    for (int n = 0; n < 4; ++n) acc[m][n] = zero;

  // intra: A (128x128) @ V_c  (K = 128)
  mm_loop(Abuf + (size_t)(b * NCn + ch) * Tn * Tn, Tn,
          Vt + ((size_t)b * Cn + d0) * Sn + t0, Sn, Tn / 32, Al, Bl, acc);
  // inter: PQ_c @ Mpre_c  (K = 512)
  if (ch > 0)
    mm_loop(PQ + ((size_t)b * Sn + t0) * Cn, Cn,
            Mpre + ((size_t)(b * NCn + ch) * Cn + d0) * Cn, Cn, Cn / 32, Al, Bl, acc);

  const int t = threadIdx.x, wid = t >> 6, lane = t & 63;
  const int wm = wid >> 1, wn = wid & 1;
#pragma unroll
  for (int m = 0; m < 4; ++m)
#pragma unroll
    for (int n = 0; n < 4; ++n) {
      const int row0 = t0 + wm * 64 + m * 16 + ((lane >> 4) << 2);
      const int col  = d0 + wn * 64 + n * 16 + (lane & 15);
      f32x4 v = acc[m][n];
#pragma unroll
      for (int j = 0; j < 4; ++j) {
        const size_t sidx = (size_t)b * Sn + row0 + j;
        out[sidx * Cn + col] = v[j] / scale[sidx];
      }
    }
}

// ---------------- launch -----------------------------------------------------
extern "C" void kernel_launch(void* const* d_in, const int* in_sizes, int n_in,
                              void* d_out, int out_size, void* d_ws, size_t ws_size,
                              hipStream_t stream)
{
  const float* x  = (const float*)d_in[0];
  const float* Wq = (const float*)d_in[1];
  const float* Wk = (const float*)d_in[2];
  const float* Wv = (const float*)d_in[3];
  float* out = (float*)d_out;

  unsigned short* xb   = (unsigned short*)d_ws;
  unsigned short* Wb   = xb   + (size_t)Bn * Sn * Cn;          // 8.39M
  unsigned short* PQ   = Wb   + (size_t)3 * Cn * Cn;           // 0.79M
  unsigned short* PK   = PQ   + (size_t)Bn * Sn * Cn;
  unsigned short* PKt  = PK   + (size_t)Bn * Sn * Cn;
  unsigned short* Vt   = PKt  + (size_t)Bn * Sn * Cn;
  unsigned short* Abuf = Vt   + (size_t)Bn * Sn * Cn;          // 2.10M
  unsigned short* Mpre = Abuf + (size_t)Bn * NCn * Tn * Tn;    // 33.55M
  float* scale = (float*)(Mpre + (size_t)Bn * NCn * Cn * Cn);  // 16K
  float* zsum  = scale + (size_t)Bn * Sn;                      // 64K
  float* zpre  = zsum  + (size_t)Bn * NCn * Cn;                // 64K
  (void)ws_size; (void)in_sizes; (void)n_in; (void)out_size;

  hipLaunchKernelGGL(k_cast_x, dim3(4096), dim3(256), 0, stream, x, xb);
  hipLaunchKernelGGL(k_cast_w, dim3(128, 3), dim3(256), 0, stream, Wq, Wk, Wv, Wb);
  hipLaunchKernelGGL(k_proj, dim3(1536), dim3(256), 0, stream, xb, Wb, PQ, PK, PKt, Vt, zsum);
  hipLaunchKernelGGL(k_zpre, dim3(Bn), dim3(512), 0, stream, zsum, zpre);
  hipLaunchKernelGGL(k_gram, dim3(NCn, Bn), dim3(256), 0, stream, PQ, PK, Abuf, scale);
  hipLaunchKernelGGL(k_scale, dim3(Sn / 4, Bn), dim3(256), 0, stream, PQ, zpre, scale);
  hipLaunchKernelGGL(k_kvp, dim3(512), dim3(256), 0, stream, PKt, Vt, Mpre);
  hipLaunchKernelGGL(k_avinter, dim3(512), dim3(256), 0, stream, Abuf, Vt, PQ, Mpre, scale, out);
}

// Round 6
// 138.587 us; speedup vs baseline: 7.0076x; 1.0087x over previous
//
#include <hip/hip_runtime.h>

// LinearAttentionCell: chunked linear attention, bf16 MFMA, traffic-minimized.
// R6: 2-phase stage-ahead double-buffered staging in all MFMA kernels
// (stage(next) -> ds_read(cur)+MFMA -> single barrier per k-step).

constexpr int Bn  = 8;
constexpr int Sn  = 2048;
constexpr int Cn  = 512;
constexpr int Tn  = 128;
constexpr int NCn = 16;
constexpr float DKf = 0.04419417382415922f;     // 1/sqrt(512)

typedef __attribute__((ext_vector_type(8))) short bf16x8;
typedef __attribute__((ext_vector_type(4))) float f32x4;

__device__ __forceinline__ unsigned short f2bf(float f) {   // RNE
  unsigned u = __float_as_uint(f);
  u = (u + 0x7fffu + ((u >> 16) & 1u)) >> 16;
  return (unsigned short)u;
}
__device__ __forceinline__ float bf2f(unsigned short h) {
  return __uint_as_float(((unsigned)h) << 16);
}
__device__ __forceinline__ float phi_f(float u) {
  float s = u * DKf;
  return s > 0.0f ? s + 1.0f : __expf(s);       // elu(s)+1
}

// ---- stage a 128x32 bf16 tile global->LDS, swizzle kslot ^= (row>>1)&3 ------
__device__ __forceinline__ void stage128x32(const unsigned short* __restrict__ g,
                                            int ld, unsigned short* lds,
                                            int wid, int lane) {
#pragma unroll
  for (int cc = 0; cc < 2; ++cc) {
    const int row = cc * 64 + wid * 16 + (lane >> 2);
    const int ks  = (lane & 3) ^ ((row >> 1) & 3);
    const unsigned short* src = g + (size_t)row * ld + ks * 8;
    unsigned short* dst = lds + (size_t)(cc * 256 + wid * 64) * 8;  // wave-uniform
    __builtin_amdgcn_global_load_lds(
        (const __attribute__((address_space(1))) void*)src,
        (__attribute__((address_space(3))) void*)dst, 16, 0, 0);
  }
}

// ---- 128x128 out tile, 4 waves (2x2 of 64x64), dbuf 2-phase K loop ----------
// Al/Bl: [2][128*32]. stage(kt+1) issued BEFORE compute(kt); one barrier/iter.
__device__ __forceinline__ void mm_loop(const unsigned short* __restrict__ Ag, int lda,
                                        const unsigned short* __restrict__ Bg, int ldb,
                                        int nkt,
                                        unsigned short* Al, unsigned short* Bl,
                                        f32x4 acc[4][4]) {
  const int t = threadIdx.x, wid = t >> 6, lane = t & 63;
  const int wm = wid >> 1, wn = wid & 1;
  const int fr = lane & 15, kb = lane >> 4;
  stage128x32(Ag, lda, Al, wid, lane);
  stage128x32(Bg, ldb, Bl, wid, lane);
  __syncthreads();                         // drains prologue loads (vmcnt0+bar)
  int cur = 0;
  for (int kt = 0; kt < nkt; ++kt) {
    const int nxt = cur ^ 1;
    if (kt + 1 < nkt) {                    // issue next-tile loads early
      stage128x32(Ag + (kt + 1) * 32, lda, Al + nxt * 4096, wid, lane);
      stage128x32(Bg + (kt + 1) * 32, ldb, Bl + nxt * 4096, wid, lane);
    }
    const unsigned short* Ac = Al + cur * 4096;
    const unsigned short* Bc = Bl + cur * 4096;
    bf16x8 af[4], bf[4];
#pragma unroll
    for (int m = 0; m < 4; ++m) {
      const int r = wm * 64 + m * 16 + fr;
      af[m] = *(const bf16x8*)&Ac[r * 32 + ((kb ^ ((r >> 1) & 3)) << 3)];
    }
#pragma unroll
    for (int n = 0; n < 4; ++n) {
      const int r = wn * 64 + n * 16 + fr;
      bf[n] = *(const bf16x8*)&Bc[r * 32 + ((kb ^ ((r >> 1) & 3)) << 3)];
    }
#pragma unroll
    for (int m = 0; m < 4; ++m)
#pragma unroll
      for (int n = 0; n < 4; ++n)
        acc[m][n] = __builtin_amdgcn_mfma_f32_16x16x32_bf16(af[m], bf[n], acc[m][n], 0, 0, 0);
    __syncthreads();                       // drains in-flight stages; guards swap
    cur = nxt;
  }
}

// ---------------- casts ------------------------------------------------------
__global__ __launch_bounds__(256) void k_cast_x(const float* __restrict__ x,
                                                unsigned short* __restrict__ xb) {
  const size_t i8 = ((size_t)blockIdx.x * 256 + threadIdx.x) * 8;
  float4 a = *(const float4*)&x[i8];
  float4 b = *(const float4*)&x[i8 + 4];
  uint4 o;
  o.x = (unsigned)f2bf(a.x) | ((unsigned)f2bf(a.y) << 16);
  o.y = (unsigned)f2bf(a.z) | ((unsigned)f2bf(a.w) << 16);
  o.z = (unsigned)f2bf(b.x) | ((unsigned)f2bf(b.y) << 16);
  o.w = (unsigned)f2bf(b.z) | ((unsigned)f2bf(b.w) << 16);
  *(uint4*)&xb[i8] = o;
}

__global__ __launch_bounds__(256) void k_cast_w(const float* __restrict__ Wq,
                                                const float* __restrict__ Wk,
                                                const float* __restrict__ Wv,
                                                unsigned short* __restrict__ Wb) {
  const int z = blockIdx.y;
  const float* __restrict__ src = (z == 0) ? Wq : (z == 1 ? Wk : Wv);
  const size_t i8 = ((size_t)blockIdx.x * 256 + threadIdx.x) * 8;
  float4 a = *(const float4*)&src[i8];
  float4 b = *(const float4*)&src[i8 + 4];
  uint4 o;
  o.x = (unsigned)f2bf(a.x) | ((unsigned)f2bf(a.y) << 16);
  o.y = (unsigned)f2bf(a.z) | ((unsigned)f2bf(a.w) << 16);
  o.z = (unsigned)f2bf(b.x) | ((unsigned)f2bf(b.y) << 16);
  o.w = (unsigned)f2bf(b.z) | ((unsigned)f2bf(b.w) << 16);
  *(uint4*)&Wb[(size_t)z * Cn * Cn + i8] = o;
}

// ---------------- K1: projections (bf16 MFMA, XCD-local m-slabs) -------------
// 1536 blocks: xcd = bid&7 owns 16 contiguous m-slabs x 4 n x 3 z
// (2 MB xb + 1.5 MB Wb per-XCD L2-resident). z==1 blocks also emit zsum.
__global__ __launch_bounds__(256) void k_proj(
    const unsigned short* __restrict__ xb, const unsigned short* __restrict__ Wb,
    unsigned short* __restrict__ PQ, unsigned short* __restrict__ PK,
    unsigned short* __restrict__ PKt, unsigned short* __restrict__ Vt,
    float* __restrict__ zsum)
{
  __shared__ unsigned short Al[2 * 128 * 32], Bl[2 * 128 * 32];
  __shared__ float zbuf[2][128];
  const int bid = blockIdx.x;
  const int xcd = bid & 7, idx = bid >> 3;            // idx in 0..191
  const int n = idx & 3, z = (idx >> 2) % 3, mloc = idx / 12;
  const int n0 = n * 128, m0 = (xcd * 16 + mloc) * 128;
  const int t = threadIdx.x, wid = t >> 6, lane = t & 63;
  const int wm = wid >> 1, wn = wid & 1;
  f32x4 acc[4][4];
  const f32x4 zero = {0.f, 0.f, 0.f, 0.f};
#pragma unroll
  for (int m = 0; m < 4; ++m)
#pragma unroll
    for (int nn = 0; nn < 4; ++nn) acc[m][nn] = zero;

  mm_loop(xb + (size_t)m0 * Cn, Cn,
          Wb + (size_t)z * Cn * Cn + (size_t)n0 * Cn, Cn, Cn / 32, Al, Bl, acc);

  float ps[4] = {0.f, 0.f, 0.f, 0.f};
#pragma unroll
  for (int m = 0; m < 4; ++m)
#pragma unroll
    for (int nn = 0; nn < 4; ++nn) {
      const int row0 = m0 + wm * 64 + m * 16 + ((lane >> 4) << 2);
      const int col  = n0 + wn * 64 + nn * 16 + (lane & 15);
      f32x4 v = acc[m][nn];
      if (z == 0) {
#pragma unroll
        for (int j = 0; j < 4; ++j)
          PQ[(size_t)(row0 + j) * Cn + col] = f2bf(phi_f(v[j]));
      } else if (z == 1) {
        ushort4 p;
#pragma unroll
        for (int j = 0; j < 4; ++j) {
          unsigned short u = f2bf(phi_f(v[j]));
          PK[(size_t)(row0 + j) * Cn + col] = u;
          (&p.x)[j] = u;
          ps[nn] += bf2f(u);
        }
        const int b = row0 >> 11, tq = row0 & (Sn - 1);
        *(ushort4*)&PKt[((size_t)b * Cn + col) * Sn + tq] = p;
      } else {
        ushort4 p;
#pragma unroll
        for (int j = 0; j < 4; ++j) (&p.x)[j] = f2bf(v[j]);
        const int b = row0 >> 11, tq = row0 & (Sn - 1);
        *(ushort4*)&Vt[((size_t)b * Cn + col) * Sn + tq] = p;
      }
    }

  if (z == 1) {   // block covers one (b, chunk) x cols n0..n0+127 completely
#pragma unroll
    for (int nn = 0; nn < 4; ++nn) {
      float v = ps[nn];
      v += __shfl_xor(v, 16); v += __shfl_xor(v, 32);   // reduce over kb
      if (lane < 16) zbuf[wm][wn * 64 + nn * 16 + lane] = v;
    }
    __syncthreads();
    if (t < 128) {
      const int b = m0 >> 11, ch = (m0 >> 7) & 15;
      zsum[((size_t)b * NCn + ch) * Cn + n0 + t] = zbuf[0][t] + zbuf[1][t];
    }
  }
}

// ---------------- K2a: A = tril(PQ_c PK_c^T) bf16, rowsum -> scale -----------
__global__ __launch_bounds__(256) void k_gram(
    const unsigned short* __restrict__ PQ, const unsigned short* __restrict__ PK,
    unsigned short* __restrict__ Abuf, float* __restrict__ scale)
{
  __shared__ unsigned short Al[2 * 128 * 32], Bl[2 * 128 * 32];
  __shared__ float rsmem[2][128];
  const int b = blockIdx.y, ch = blockIdx.x;
  const size_t base = ((size_t)b * Sn + ch * Tn) * Cn;
  f32x4 acc[4][4];
  const f32x4 zero = {0.f, 0.f, 0.f, 0.f};
#pragma unroll
  for (int m = 0; m < 4; ++m)
#pragma unroll
    for (int n = 0; n < 4; ++n) acc[m][n] = zero;

  mm_loop(PQ + base, Cn, PK + base, Cn, Cn / 32, Al, Bl, acc);

  const int t = threadIdx.x, wid = t >> 6, lane = t & 63;
  const int wm = wid >> 1, wn = wid & 1;
  float rsum[4][4];
#pragma unroll
  for (int m = 0; m < 4; ++m)
#pragma unroll
    for (int j = 0; j < 4; ++j) rsum[m][j] = 0.f;
#pragma unroll
  for (int m = 0; m < 4; ++m)
#pragma unroll
    for (int n = 0; n < 4; ++n) {
      f32x4 v = acc[m][n];
#pragma unroll
      for (int j = 0; j < 4; ++j) {
        const int row = wm * 64 + m * 16 + ((lane >> 4) << 2) + j;
        const int col = wn * 64 + n * 16 + (lane & 15);
        unsigned short u = (col <= row) ? f2bf(v[j]) : 0;
        Abuf[((size_t)(b * NCn + ch) * Tn + row) * Tn + col] = u;
        rsum[m][j] += bf2f(u);          // rowsum over the SAME rounded values
      }
    }
#pragma unroll
  for (int m = 0; m < 4; ++m)
#pragma unroll
    for (int j = 0; j < 4; ++j) {
      float r = rsum[m][j];
      r += __shfl_xor(r, 1); r += __shfl_xor(r, 2);
      r += __shfl_xor(r, 4); r += __shfl_xor(r, 8);
      if ((lane & 15) == 0)
        rsmem[wn][wm * 64 + m * 16 + ((lane >> 4) << 2) + j] = r;
    }
  __syncthreads();
  if (t < 128)
    scale[(size_t)b * Sn + ch * Tn + t] = rsmem[0][t] + rsmem[1][t];
}

// ---------------- Kz: zpre + scale finalize ----------------------------------
__global__ __launch_bounds__(512) void k_zpre(const float* __restrict__ zsum,
                                              float* __restrict__ zpre) {
  const int b = blockIdx.x, c = threadIdx.x;
  float run = 0.f;
  for (int ch = 0; ch < NCn; ++ch) {
    zpre[((size_t)b * NCn + ch) * Cn + c] = run;
    run += zsum[((size_t)b * NCn + ch) * Cn + c];
  }
}

__global__ __launch_bounds__(256) void k_scale(const unsigned short* __restrict__ PQ,
                                               const float* __restrict__ zpre,
                                               float* __restrict__ scale) {
  const int b = blockIdx.y;
  const int w = threadIdx.x >> 6, lane = threadIdx.x & 63;
  const int row = blockIdx.x * 4 + w;
  const int ch = row >> 7;
  const unsigned short* pq = PQ + ((size_t)b * Sn + row) * Cn + lane * 8;
  const float* zp = zpre + ((size_t)b * NCn + ch) * Cn + lane * 8;
  uint4 q = *(const uint4*)pq;
  float4 z0 = *(const float4*)zp, z1 = *(const float4*)(zp + 4);
  float d = bf2f((unsigned short)(q.x & 0xffff)) * z0.x
          + bf2f((unsigned short)(q.x >> 16))    * z0.y
          + bf2f((unsigned short)(q.y & 0xffff)) * z0.z
          + bf2f((unsigned short)(q.y >> 16))    * z0.w
          + bf2f((unsigned short)(q.z & 0xffff)) * z1.x
          + bf2f((unsigned short)(q.z >> 16))    * z1.y
          + bf2f((unsigned short)(q.w & 0xffff)) * z1.z
          + bf2f((unsigned short)(q.w >> 16))    * z1.w;
#pragma unroll
  for (int off = 32; off > 0; off >>= 1) d += __shfl_xor(d, off);
  if (lane == 0) scale[(size_t)b * Sn + row] += d + 1e-5f;
}

// ---- stage a 64x128 bf16 tile global->LDS, swizzle slot ^= row&7 ------------
__device__ __forceinline__ void stage64x128(const unsigned short* __restrict__ g,
                                            int ld, unsigned short* lds,
                                            int wid, int lane) {
#pragma unroll
  for (int i = 0; i < 4; ++i) {
    const int row = wid * 16 + i * 4 + (lane >> 4);
    const int s   = (lane & 15) ^ (row & 7);
    const unsigned short* src = g + (size_t)row * ld + s * 8;
    unsigned short* dst = lds + (size_t)(wid * 16 + i * 4) * 128;   // wave-uniform
    __builtin_amdgcn_global_load_lds(
        (const __attribute__((address_space(1))) void*)src,
        (__attribute__((address_space(3))) void*)dst, 16, 0, 0);
  }
}

// ---------------- K3a: fused KV + exclusive prefix (BK=128, dbuf 2-phase) ----
// 512 blocks; XCD k owns batch k (PKt/Vt ~4 MB L2). Block owns a 64(c)x64(d)
// tile of M; per chunk: stage ch+1, write running prefix (bf16), accumulate ch.
__global__ __launch_bounds__(256) void k_kvp(
    const unsigned short* __restrict__ PKt, const unsigned short* __restrict__ Vt,
    unsigned short* __restrict__ Mpre)
{
  __shared__ unsigned short Al[2 * 64 * 128], Bl[2 * 64 * 128];
  const int bid = blockIdx.x;
  const int b = bid & 7, idx = bid >> 3;
  const int d0 = (idx & 7) * 64, c0 = (idx >> 3) * 64;
  const int t = threadIdx.x, wid = t >> 6, lane = t & 63;
  const int wm = wid >> 1, wn = wid & 1;
  const int fr = lane & 15, kb = lane >> 4;
  f32x4 acc[2][2];
  const f32x4 zero = {0.f, 0.f, 0.f, 0.f};
#pragma unroll
  for (int m = 0; m < 2; ++m)
#pragma unroll
    for (int n = 0; n < 2; ++n) acc[m][n] = zero;
  const unsigned short* Ag = PKt + ((size_t)b * Cn + c0) * Sn;
  const unsigned short* Bg = Vt  + ((size_t)b * Cn + d0) * Sn;
  stage64x128(Ag, Sn, Al, wid, lane);
  stage64x128(Bg, Sn, Bl, wid, lane);
  __syncthreads();
  int cur = 0;
  for (int ch = 0; ch < NCn; ++ch) {
    const int nxt = cur ^ 1;
    if (ch + 1 < NCn) {                  // issue next-chunk loads early
      stage64x128(Ag + (ch + 1) * Tn, Sn, Al + nxt * 8192, wid, lane);
      stage64x128(Bg + (ch + 1) * Tn, Sn, Bl + nxt * 8192, wid, lane);
    }
    if (ch > 0) {   // Mpre[ch] = sum of chunks < ch (Mpre[0] never read)
#pragma unroll
      for (int m = 0; m < 2; ++m)
#pragma unroll
        for (int n = 0; n < 2; ++n) {
          const int c_row = c0 + wm * 32 + m * 16 + (kb << 2);
          const int d     = d0 + wn * 32 + n * 16 + fr;
          ushort4 p;
#pragma unroll
          for (int j = 0; j < 4; ++j) (&p.x)[j] = f2bf(acc[m][n][j]);
          *(ushort4*)&Mpre[((size_t)(b * NCn + ch) * Cn + d) * Cn + c_row] = p;
        }
    }
    const unsigned short* Ac = Al + cur * 8192;
    const unsigned short* Bc = Bl + cur * 8192;
#pragma unroll
    for (int kt = 0; kt < 4; ++kt) {
      bf16x8 af[2], bf[2];
#pragma unroll
      for (int m = 0; m < 2; ++m) {
        const int r = wm * 32 + m * 16 + fr;
        af[m] = *(const bf16x8*)&Ac[r * 128 + (((kt * 4 + kb) ^ (r & 7)) << 3)];
      }
#pragma unroll
      for (int n = 0; n < 2; ++n) {
        const int r = wn * 32 + n * 16 + fr;
        bf[n] = *(const bf16x8*)&Bc[r * 128 + (((kt * 4 + kb) ^ (r & 7)) << 3)];
      }
#pragma unroll
      for (int m = 0; m < 2; ++m)
#pragma unroll
        for (int n = 0; n < 2; ++n)
          acc[m][n] = __builtin_amdgcn_mfma_f32_16x16x32_bf16(af[m], bf[n], acc[m][n], 0, 0, 0);
    }
    __syncthreads();
    cur = nxt;
  }
}

// ---------------- K3b: out = (A@V_c + PQ_c@Mpre_c) / scale (single write) ----
__global__ __launch_bounds__(256) void k_avinter(
    const unsigned short* __restrict__ Abuf, const unsigned short* __restrict__ Vt,
    const unsigned short* __restrict__ PQ, const unsigned short* __restrict__ Mpre,
    const float* __restrict__ scale, float* __restrict__ out)
{
  __shared__ unsigned short Al[2 * 128 * 32], Bl[2 * 128 * 32];
  const int bid = blockIdx.x;
  const int logical = (bid & 7) * 64 + (bid >> 3);
  const int d0 = (logical & 3) * 128;
  const int ch = (logical >> 2) & 15;
  const int b  = logical >> 6;
  const int t0 = ch * Tn;
  f32x4 acc[4][4];
  const f32x4 zero = {0.f, 0.f, 0.f, 0.f};
#pragma unroll
  for (int m = 0; m < 4; ++m)
#pragma unroll
    for (int n = 0; n < 4; ++n) acc[m][n] = zero;

  // intra: A (128x128) @ V_c  (K = 128)
  mm_loop(Abuf + (size_t)(b * NCn + ch) * Tn * Tn, Tn,
          Vt + ((size_t)b * Cn + d0) * Sn + t0, Sn, Tn / 32, Al, Bl, acc);
  // inter: PQ_c @ Mpre_c  (K = 512)
  if (ch > 0)
    mm_loop(PQ + ((size_t)b * Sn + t0) * Cn, Cn,
            Mpre + ((size_t)(b * NCn + ch) * Cn + d0) * Cn, Cn, Cn / 32, Al, Bl, acc);

  const int t = threadIdx.x, wid = t >> 6, lane = t & 63;
  const int wm = wid >> 1, wn = wid & 1;
#pragma unroll
  for (int m = 0; m < 4; ++m)
#pragma unroll
    for (int n = 0; n < 4; ++n) {
      const int row0 = t0 + wm * 64 + m * 16 + ((lane >> 4) << 2);
      const int col  = d0 + wn * 64 + n * 16 + (lane & 15);
      f32x4 v = acc[m][n];
#pragma unroll
      for (int j = 0; j < 4; ++j) {
        const size_t sidx = (size_t)b * Sn + row0 + j;
        out[sidx * Cn + col] = v[j] / scale[sidx];
      }
    }
}

// ---------------- launch -----------------------------------------------------
extern "C" void kernel_launch(void* const* d_in, const int* in_sizes, int n_in,
                              void* d_out, int out_size, void* d_ws, size_t ws_size,
                              hipStream_t stream)
{
  const float* x  = (const float*)d_in[0];
  const float* Wq = (const float*)d_in[1];
  const float* Wk = (const float*)d_in[2];
  const float* Wv = (const float*)d_in[3];
  float* out = (float*)d_out;

  unsigned short* xb   = (unsigned short*)d_ws;
  unsigned short* Wb   = xb   + (size_t)Bn * Sn * Cn;          // 8.39M
  unsigned short* PQ   = Wb   + (size_t)3 * Cn * Cn;           // 0.79M
  unsigned short* PK   = PQ   + (size_t)Bn * Sn * Cn;
  unsigned short* PKt  = PK   + (size_t)Bn * Sn * Cn;
  unsigned short* Vt   = PKt  + (size_t)Bn * Sn * Cn;
  unsigned short* Abuf = Vt   + (size_t)Bn * Sn * Cn;          // 2.10M
  unsigned short* Mpre = Abuf + (size_t)Bn * NCn * Tn * Tn;    // 33.55M
  float* scale = (float*)(Mpre + (size_t)Bn * NCn * Cn * Cn);  // 16K
  float* zsum  = scale + (size_t)Bn * Sn;                      // 64K
  float* zpre  = zsum  + (size_t)Bn * NCn * Cn;                // 64K
  (void)ws_size; (void)in_sizes; (void)n_in; (void)out_size;

  hipLaunchKernelGGL(k_cast_x, dim3(4096), dim3(256), 0, stream, x, xb);
  hipLaunchKernelGGL(k_cast_w, dim3(128, 3), dim3(256), 0, stream, Wq, Wk, Wv, Wb);
  hipLaunchKernelGGL(k_proj, dim3(1536), dim3(256), 0, stream, xb, Wb, PQ, PK, PKt, Vt, zsum);
  hipLaunchKernelGGL(k_zpre, dim3(Bn), dim3(512), 0, stream, zsum, zpre);
  hipLaunchKernelGGL(k_gram, dim3(NCn, Bn), dim3(256), 0, stream, PQ, PK, Abuf, scale);
  hipLaunchKernelGGL(k_scale, dim3(Sn / 4, Bn), dim3(256), 0, stream, PQ, zpre, scale);
  hipLaunchKernelGGL(k_kvp, dim3(512), dim3(256), 0, stream, PKt, Vt, Mpre);
  hipLaunchKernelGGL(k_avinter, dim3(512), dim3(256), 0, stream, Abuf, Vt, PQ, Mpre, scale, out);
}

// Round 7
// 133.899 us; speedup vs baseline: 7.2530x; 1.0350x over previous
//
#include <hip/hip_runtime.h>

// LinearAttentionCell: chunked linear attention, bf16 MFMA.
// R7: counted-vmcnt pipelined K-loops (raw s_barrier + s_waitcnt vmcnt(N),
// loads stay in flight across MFMA phase); zpre+scale fused into gram.

constexpr int Bn  = 8;
constexpr int Sn  = 2048;
constexpr int Cn  = 512;
constexpr int Tn  = 128;
constexpr int NCn = 16;
constexpr float DKf = 0.04419417382415922f;     // 1/sqrt(512)

typedef __attribute__((ext_vector_type(8))) short bf16x8;
typedef __attribute__((ext_vector_type(4))) float f32x4;

__device__ __forceinline__ unsigned short f2bf(float f) {   // RNE
  unsigned u = __float_as_uint(f);
  u = (u + 0x7fffu + ((u >> 16) & 1u)) >> 16;
  return (unsigned short)u;
}
__device__ __forceinline__ float bf2f(unsigned short h) {
  return __uint_as_float(((unsigned)h) << 16);
}
__device__ __forceinline__ float phi_f(float u) {
  float s = u * DKf;
  return s > 0.0f ? s + 1.0f : __expf(s);       // elu(s)+1
}

// ---- stage a 128x32 bf16 tile global->LDS, swizzle kslot ^= (row>>1)&3 ------
__device__ __forceinline__ void stage128x32(const unsigned short* __restrict__ g,
                                            int ld, unsigned short* lds,
                                            int wid, int lane) {
#pragma unroll
  for (int cc = 0; cc < 2; ++cc) {
    const int row = cc * 64 + wid * 16 + (lane >> 2);
    const int ks  = (lane & 3) ^ ((row >> 1) & 3);
    const unsigned short* src = g + (size_t)row * ld + ks * 8;
    unsigned short* dst = lds + (size_t)(cc * 256 + wid * 64) * 8;  // wave-uniform
    __builtin_amdgcn_global_load_lds(
        (const __attribute__((address_space(1))) void*)src,
        (__attribute__((address_space(3))) void*)dst, 16, 0, 0);
  }
}

// ---- 128x128 out tile, 4 waves (2x2 of 64x64), counted-vmcnt dbuf K loop ----
// Per iter: issue stage(kt+1) [4 loads/thread] -> vmcnt(4) waits ONLY the
// previous tile's loads -> s_barrier -> ds_read+MFMA -> s_barrier. The 4 new
// loads stay in flight under the MFMA phase (tail iter drains with vmcnt(0)).
__device__ __forceinline__ void mm_loop(const unsigned short* __restrict__ Ag, int lda,
                                        const unsigned short* __restrict__ Bg, int ldb,
                                        int nkt,
                                        unsigned short* Al, unsigned short* Bl,
                                        f32x4 acc[4][4]) {
  const int t = threadIdx.x, wid = t >> 6, lane = t & 63;
  const int wm = wid >> 1, wn = wid & 1;
  const int fr = lane & 15, kb = lane >> 4;
  stage128x32(Ag, lda, Al, wid, lane);
  stage128x32(Bg, ldb, Bl, wid, lane);
  int cur = 0;
  for (int kt = 0; kt < nkt; ++kt) {
    const int nxt = cur ^ 1;
    if (kt + 1 < nkt) {
      stage128x32(Ag + (kt + 1) * 32, lda, Al + nxt * 4096, wid, lane);
      stage128x32(Bg + (kt + 1) * 32, ldb, Bl + nxt * 4096, wid, lane);
      asm volatile("s_waitcnt vmcnt(4)" ::: "memory");
    } else {
      asm volatile("s_waitcnt vmcnt(0)" ::: "memory");
    }
    __builtin_amdgcn_s_barrier();
    asm volatile("" ::: "memory");          // no ds_read hoist above barrier
    const unsigned short* Ac = Al + cur * 4096;
    const unsigned short* Bc = Bl + cur * 4096;
    bf16x8 af[4], bf[4];
#pragma unroll
    for (int m = 0; m < 4; ++m) {
      const int r = wm * 64 + m * 16 + fr;
      af[m] = *(const bf16x8*)&Ac[r * 32 + ((kb ^ ((r >> 1) & 3)) << 3)];
    }
#pragma unroll
    for (int n = 0; n < 4; ++n) {
      const int r = wn * 64 + n * 16 + fr;
      bf[n] = *(const bf16x8*)&Bc[r * 32 + ((kb ^ ((r >> 1) & 3)) << 3)];
    }
#pragma unroll
    for (int m = 0; m < 4; ++m)
#pragma unroll
      for (int n = 0; n < 4; ++n)
        acc[m][n] = __builtin_amdgcn_mfma_f32_16x16x32_bf16(af[m], bf[n], acc[m][n], 0, 0, 0);
    __builtin_amdgcn_s_barrier();           // all waves done reading cur
    asm volatile("" ::: "memory");
    cur = nxt;
  }
}

// ---------------- casts ------------------------------------------------------
__global__ __launch_bounds__(256) void k_cast_x(const float* __restrict__ x,
                                                unsigned short* __restrict__ xb) {
  const size_t i8 = ((size_t)blockIdx.x * 256 + threadIdx.x) * 8;
  float4 a = *(const float4*)&x[i8];
  float4 b = *(const float4*)&x[i8 + 4];
  uint4 o;
  o.x = (unsigned)f2bf(a.x) | ((unsigned)f2bf(a.y) << 16);
  o.y = (unsigned)f2bf(a.z) | ((unsigned)f2bf(a.w) << 16);
  o.z = (unsigned)f2bf(b.x) | ((unsigned)f2bf(b.y) << 16);
  o.w = (unsigned)f2bf(b.z) | ((unsigned)f2bf(b.w) << 16);
  *(uint4*)&xb[i8] = o;
}

__global__ __launch_bounds__(256) void k_cast_w(const float* __restrict__ Wq,
                                                const float* __restrict__ Wk,
                                                const float* __restrict__ Wv,
                                                unsigned short* __restrict__ Wb) {
  const int z = blockIdx.y;
  const float* __restrict__ src = (z == 0) ? Wq : (z == 1 ? Wk : Wv);
  const size_t i8 = ((size_t)blockIdx.x * 256 + threadIdx.x) * 8;
  float4 a = *(const float4*)&src[i8];
  float4 b = *(const float4*)&src[i8 + 4];
  uint4 o;
  o.x = (unsigned)f2bf(a.x) | ((unsigned)f2bf(a.y) << 16);
  o.y = (unsigned)f2bf(a.z) | ((unsigned)f2bf(a.w) << 16);
  o.z = (unsigned)f2bf(b.x) | ((unsigned)f2bf(b.y) << 16);
  o.w = (unsigned)f2bf(b.z) | ((unsigned)f2bf(b.w) << 16);
  *(uint4*)&Wb[(size_t)z * Cn * Cn + i8] = o;
}

// ---------------- K1: projections (bf16 MFMA, XCD-local m-slabs) -------------
__global__ __launch_bounds__(256) void k_proj(
    const unsigned short* __restrict__ xb, const unsigned short* __restrict__ Wb,
    unsigned short* __restrict__ PQ, unsigned short* __restrict__ PK,
    unsigned short* __restrict__ PKt, unsigned short* __restrict__ Vt,
    float* __restrict__ zsum)
{
  __shared__ unsigned short Al[2 * 128 * 32], Bl[2 * 128 * 32];
  __shared__ float zbuf[2][128];
  const int bid = blockIdx.x;
  const int xcd = bid & 7, idx = bid >> 3;            // idx in 0..191
  const int n = idx & 3, z = (idx >> 2) % 3, mloc = idx / 12;
  const int n0 = n * 128, m0 = (xcd * 16 + mloc) * 128;
  const int t = threadIdx.x, wid = t >> 6, lane = t & 63;
  const int wm = wid >> 1, wn = wid & 1;
  f32x4 acc[4][4];
  const f32x4 zero = {0.f, 0.f, 0.f, 0.f};
#pragma unroll
  for (int m = 0; m < 4; ++m)
#pragma unroll
    for (int nn = 0; nn < 4; ++nn) acc[m][nn] = zero;

  mm_loop(xb + (size_t)m0 * Cn, Cn,
          Wb + (size_t)z * Cn * Cn + (size_t)n0 * Cn, Cn, Cn / 32, Al, Bl, acc);

  float ps[4] = {0.f, 0.f, 0.f, 0.f};
#pragma unroll
  for (int m = 0; m < 4; ++m)
#pragma unroll
    for (int nn = 0; nn < 4; ++nn) {
      const int row0 = m0 + wm * 64 + m * 16 + ((lane >> 4) << 2);
      const int col  = n0 + wn * 64 + nn * 16 + (lane & 15);
      f32x4 v = acc[m][nn];
      if (z == 0) {
#pragma unroll
        for (int j = 0; j < 4; ++j)
          PQ[(size_t)(row0 + j) * Cn + col] = f2bf(phi_f(v[j]));
      } else if (z == 1) {
        ushort4 p;
#pragma unroll
        for (int j = 0; j < 4; ++j) {
          unsigned short u = f2bf(phi_f(v[j]));
          PK[(size_t)(row0 + j) * Cn + col] = u;
          (&p.x)[j] = u;
          ps[nn] += bf2f(u);
        }
        const int b = row0 >> 11, tq = row0 & (Sn - 1);
        *(ushort4*)&PKt[((size_t)b * Cn + col) * Sn + tq] = p;
      } else {
        ushort4 p;
#pragma unroll
        for (int j = 0; j < 4; ++j) (&p.x)[j] = f2bf(v[j]);
        const int b = row0 >> 11, tq = row0 & (Sn - 1);
        *(ushort4*)&Vt[((size_t)b * Cn + col) * Sn + tq] = p;
      }
    }

  if (z == 1) {   // block covers one (b, chunk) x cols n0..n0+127 completely
#pragma unroll
    for (int nn = 0; nn < 4; ++nn) {
      float v = ps[nn];
      v += __shfl_xor(v, 16); v += __shfl_xor(v, 32);   // reduce over kb
      if (lane < 16) zbuf[wm][wn * 64 + nn * 16 + lane] = v;
    }
    __syncthreads();
    if (t < 128) {
      const int b = m0 >> 11, ch = (m0 >> 7) & 15;
      zsum[((size_t)b * NCn + ch) * Cn + n0 + t] = zbuf[0][t] + zbuf[1][t];
    }
  }
}

// ---------------- K2a: A = tril(PQ_c PK_c^T) bf16; scale fully fused ---------
// scale[row] = rowsum(tril) + dot(PQ_row, zpre[b][ch]) + 1e-5, zpre from zsum.
__global__ __launch_bounds__(256) void k_gram(
    const unsigned short* __restrict__ PQ, const unsigned short* __restrict__ PK,
    const float* __restrict__ zsum,
    unsigned short* __restrict__ Abuf, float* __restrict__ scale)
{
  __shared__ unsigned short Al[2 * 128 * 32], Bl[2 * 128 * 32];
  __shared__ float rsmem[2][128];
  __shared__ float zpl[512];
  const int b = blockIdx.y, ch = blockIdx.x;
  const size_t base = ((size_t)b * Sn + ch * Tn) * Cn;
  f32x4 acc[4][4];
  const f32x4 zero = {0.f, 0.f, 0.f, 0.f};
#pragma unroll
  for (int m = 0; m < 4; ++m)
#pragma unroll
    for (int n = 0; n < 4; ++n) acc[m][n] = zero;

  mm_loop(PQ + base, Cn, PK + base, Cn, Cn / 32, Al, Bl, acc);

  const int t = threadIdx.x, wid = t >> 6, lane = t & 63;
  const int wm = wid >> 1, wn = wid & 1;
  float rsum[4][4];
#pragma unroll
  for (int m = 0; m < 4; ++m)
#pragma unroll
    for (int j = 0; j < 4; ++j) rsum[m][j] = 0.f;
#pragma unroll
  for (int m = 0; m < 4; ++m)
#pragma unroll
    for (int n = 0; n < 4; ++n) {
      f32x4 v = acc[m][n];
#pragma unroll
      for (int j = 0; j < 4; ++j) {
        const int row = wm * 64 + m * 16 + ((lane >> 4) << 2) + j;
        const int col = wn * 64 + n * 16 + (lane & 15);
        unsigned short u = (col <= row) ? f2bf(v[j]) : 0;
        Abuf[((size_t)(b * NCn + ch) * Tn + row) * Tn + col] = u;
        rsum[m][j] += bf2f(u);          // rowsum over the SAME rounded values
      }
    }
#pragma unroll
  for (int m = 0; m < 4; ++m)
#pragma unroll
    for (int j = 0; j < 4; ++j) {
      float r = rsum[m][j];
      r += __shfl_xor(r, 1); r += __shfl_xor(r, 2);
      r += __shfl_xor(r, 4); r += __shfl_xor(r, 8);
      if ((lane & 15) == 0)
        rsmem[wn][wm * 64 + m * 16 + ((lane >> 4) << 2) + j] = r;
    }
  // exclusive chunk-prefix of zsum -> zpl (LDS)
#pragma unroll
  for (int e = 0; e < 2; ++e) {
    const int c = t + e * 256;
    float s = 0.f;
    for (int ch2 = 0; ch2 < ch; ++ch2)
      s += zsum[((size_t)b * NCn + ch2) * Cn + c];
    zpl[c] = s;
  }
  __syncthreads();
  // per-row dot(PQ_row, zpl) + finalize scale (2 threads per row)
  const int row = t >> 1, half = (t & 1) * 256;
  const unsigned short* pq = PQ + base + (size_t)row * Cn + half;
  float dacc = 0.f;
  for (int i = 0; i < 256; i += 8) {
    uint4 q = *(const uint4*)(pq + i);
    dacc += bf2f((unsigned short)(q.x & 0xffff)) * zpl[half + i + 0]
          + bf2f((unsigned short)(q.x >> 16))    * zpl[half + i + 1]
          + bf2f((unsigned short)(q.y & 0xffff)) * zpl[half + i + 2]
          + bf2f((unsigned short)(q.y >> 16))    * zpl[half + i + 3]
          + bf2f((unsigned short)(q.z & 0xffff)) * zpl[half + i + 4]
          + bf2f((unsigned short)(q.z >> 16))    * zpl[half + i + 5]
          + bf2f((unsigned short)(q.w & 0xffff)) * zpl[half + i + 6]
          + bf2f((unsigned short)(q.w >> 16))    * zpl[half + i + 7];
  }
  dacc += __shfl_xor(dacc, 1);
  if ((t & 1) == 0)
    scale[(size_t)b * Sn + ch * Tn + row] =
        rsmem[0][row] + rsmem[1][row] + dacc + 1e-5f;
}

// ---- stage a 64x128 bf16 tile global->LDS, swizzle slot ^= row&7 ------------
__device__ __forceinline__ void stage64x128(const unsigned short* __restrict__ g,
                                            int ld, unsigned short* lds,
                                            int wid, int lane) {
#pragma unroll
  for (int i = 0; i < 4; ++i) {
    const int row = wid * 16 + i * 4 + (lane >> 4);
    const int s   = (lane & 15) ^ (row & 7);
    const unsigned short* src = g + (size_t)row * ld + s * 8;
    unsigned short* dst = lds + (size_t)(wid * 16 + i * 4) * 128;   // wave-uniform
    __builtin_amdgcn_global_load_lds(
        (const __attribute__((address_space(1))) void*)src,
        (__attribute__((address_space(3))) void*)dst, 16, 0, 0);
  }
}

// ---------------- K3a: fused KV + exclusive prefix (BK=128, counted vmcnt) ---
// 512 blocks; XCD k owns batch k. Block owns 64(c)x64(d) of M; per chunk:
// stage ch+1 (8 loads) -> vmcnt(8) -> barrier -> write prefix -> MFMA ch.
__global__ __launch_bounds__(256) void k_kvp(
    const unsigned short* __restrict__ PKt, const unsigned short* __restrict__ Vt,
    unsigned short* __restrict__ Mpre)
{
  __shared__ unsigned short Al[2 * 64 * 128], Bl[2 * 64 * 128];
  const int bid = blockIdx.x;
  const int b = bid & 7, idx = bid >> 3;
  const int d0 = (idx & 7) * 64, c0 = (idx >> 3) * 64;
  const int t = threadIdx.x, wid = t >> 6, lane = t & 63;
  const int wm = wid >> 1, wn = wid & 1;
  const int fr = lane & 15, kb = lane >> 4;
  f32x4 acc[2][2];
  const f32x4 zero = {0.f, 0.f, 0.f, 0.f};
#pragma unroll
  for (int m = 0; m < 2; ++m)
#pragma unroll
    for (int n = 0; n < 2; ++n) acc[m][n] = zero;
  const unsigned short* Ag = PKt + ((size_t)b * Cn + c0) * Sn;
  const unsigned short* Bg = Vt  + ((size_t)b * Cn + d0) * Sn;
  stage64x128(Ag, Sn, Al, wid, lane);
  stage64x128(Bg, Sn, Bl, wid, lane);
  int cur = 0;
  for (int ch = 0; ch < NCn; ++ch) {
    const int nxt = cur ^ 1;
    if (ch + 1 < NCn) {
      stage64x128(Ag + (ch + 1) * Tn, Sn, Al + nxt * 8192, wid, lane);
      stage64x128(Bg + (ch + 1) * Tn, Sn, Bl + nxt * 8192, wid, lane);
      asm volatile("s_waitcnt vmcnt(8)" ::: "memory");
    } else {
      asm volatile("s_waitcnt vmcnt(0)" ::: "memory");
    }
    __builtin_amdgcn_s_barrier();
    asm volatile("" ::: "memory");
    if (ch > 0) {   // Mpre[ch] = sum of chunks < ch (Mpre[0] never read)
#pragma unroll
      for (int m = 0; m < 2; ++m)
#pragma unroll
        for (int n = 0; n < 2; ++n) {
          const int c_row = c0 + wm * 32 + m * 16 + (kb << 2);
          const int d     = d0 + wn * 32 + n * 16 + fr;
          ushort4 p;
#pragma unroll
          for (int j = 0; j < 4; ++j) (&p.x)[j] = f2bf(acc[m][n][j]);
          *(ushort4*)&Mpre[((size_t)(b * NCn + ch) * Cn + d) * Cn + c_row] = p;
        }
    }
    const unsigned short* Ac = Al + cur * 8192;
    const unsigned short* Bc = Bl + cur * 8192;
#pragma unroll
    for (int kt = 0; kt < 4; ++kt) {
      bf16x8 af[2], bf[2];
#pragma unroll
      for (int m = 0; m < 2; ++m) {
        const int r = wm * 32 + m * 16 + fr;
        af[m] = *(const bf16x8*)&Ac[r * 128 + (((kt * 4 + kb) ^ (r & 7)) << 3)];
      }
#pragma unroll
      for (int n = 0; n < 2; ++n) {
        const int r = wn * 32 + n * 16 + fr;
        bf[n] = *(const bf16x8*)&Bc[r * 128 + (((kt * 4 + kb) ^ (r & 7)) << 3)];
      }
#pragma unroll
      for (int m = 0; m < 2; ++m)
#pragma unroll
        for (int n = 0; n < 2; ++n)
          acc[m][n] = __builtin_amdgcn_mfma_f32_16x16x32_bf16(af[m], bf[n], acc[m][n], 0, 0, 0);
    }
    __builtin_amdgcn_s_barrier();
    asm volatile("" ::: "memory");
    cur = nxt;
  }
}

// ---------------- K3b: out = (A@V_c + PQ_c@Mpre_c) / scale (single write) ----
__global__ __launch_bounds__(256) void k_avinter(
    const unsigned short* __restrict__ Abuf, const unsigned short* __restrict__ Vt,
    const unsigned short* __restrict__ PQ, const unsigned short* __restrict__ Mpre,
    const float* __restrict__ scale, float* __restrict__ out)
{
  __shared__ unsigned short Al[2 * 128 * 32], Bl[2 * 128 * 32];
  const int bid = blockIdx.x;
  const int logical = (bid & 7) * 64 + (bid >> 3);
  const int d0 = (logical & 3) * 128;
  const int ch = (logical >> 2) & 15;
  const int b  = logical >> 6;
  const int t0 = ch * Tn;
  f32x4 acc[4][4];
  const f32x4 zero = {0.f, 0.f, 0.f, 0.f};
#pragma unroll
  for (int m = 0; m < 4; ++m)
#pragma unroll
    for (int n = 0; n < 4; ++n) acc[m][n] = zero;

  // intra: A (128x128) @ V_c  (K = 128)
  mm_loop(Abuf + (size_t)(b * NCn + ch) * Tn * Tn, Tn,
          Vt + ((size_t)b * Cn + d0) * Sn + t0, Sn, Tn / 32, Al, Bl, acc);
  // inter: PQ_c @ Mpre_c  (K = 512)
  if (ch > 0)
    mm_loop(PQ + ((size_t)b * Sn + t0) * Cn, Cn,
            Mpre + ((size_t)(b * NCn + ch) * Cn + d0) * Cn, Cn, Cn / 32, Al, Bl, acc);

  const int t = threadIdx.x, wid = t >> 6, lane = t & 63;
  const int wm = wid >> 1, wn = wid & 1;
#pragma unroll
  for (int m = 0; m < 4; ++m)
#pragma unroll
    for (int n = 0; n < 4; ++n) {
      const int row0 = t0 + wm * 64 + m * 16 + ((lane >> 4) << 2);
      const int col  = d0 + wn * 64 + n * 16 + (lane & 15);
      f32x4 v = acc[m][n];
#pragma unroll
      for (int j = 0; j < 4; ++j) {
        const size_t sidx = (size_t)b * Sn + row0 + j;
        out[sidx * Cn + col] = v[j] / scale[sidx];
      }
    }
}

// ---------------- launch -----------------------------------------------------
extern "C" void kernel_launch(void* const* d_in, const int* in_sizes, int n_in,
                              void* d_out, int out_size, void* d_ws, size_t ws_size,
                              hipStream_t stream)
{
  const float* x  = (const float*)d_in[0];
  const float* Wq = (const float*)d_in[1];
  const float* Wk = (const float*)d_in[2];
  const float* Wv = (const float*)d_in[3];
  float* out = (float*)d_out;

  unsigned short* xb   = (unsigned short*)d_ws;
  unsigned short* Wb   = xb   + (size_t)Bn * Sn * Cn;          // 8.39M
  unsigned short* PQ   = Wb   + (size_t)3 * Cn * Cn;           // 0.79M
  unsigned short* PK   = PQ   + (size_t)Bn * Sn * Cn;
  unsigned short* PKt  = PK   + (size_t)Bn * Sn * Cn;
  unsigned short* Vt   = PKt  + (size_t)Bn * Sn * Cn;
  unsigned short* Abuf = Vt   + (size_t)Bn * Sn * Cn;          // 2.10M
  unsigned short* Mpre = Abuf + (size_t)Bn * NCn * Tn * Tn;    // 33.55M
  float* scale = (float*)(Mpre + (size_t)Bn * NCn * Cn * Cn);  // 16K
  float* zsum  = scale + (size_t)Bn * Sn;                      // 64K
  (void)ws_size; (void)in_sizes; (void)n_in; (void)out_size;

  hipLaunchKernelGGL(k_cast_x, dim3(4096), dim3(256), 0, stream, x, xb);
  hipLaunchKernelGGL(k_cast_w, dim3(128, 3), dim3(256), 0, stream, Wq, Wk, Wv, Wb);
  hipLaunchKernelGGL(k_proj, dim3(1536), dim3(256), 0, stream, xb, Wb, PQ, PK, PKt, Vt, zsum);
  hipLaunchKernelGGL(k_gram, dim3(NCn, Bn), dim3(256), 0, stream, PQ, PK, zsum, Abuf, scale);
  hipLaunchKernelGGL(k_kvp, dim3(512), dim3(256), 0, stream, PKt, Vt, Mpre);
  hipLaunchKernelGGL(k_avinter, dim3(512), dim3(256), 0, stream, Abuf, Vt, PQ, Mpre, scale, out);
}

// Round 8
// 132.243 us; speedup vs baseline: 7.3438x; 1.0125x over previous
//
#include <hip/hip_runtime.h>

// LinearAttentionCell: chunked linear attention, bf16 MFMA.
// R8: 3-buffer prefetch-distance-2 K-loop (stage kt+2, vmcnt(8) waits the
// tile issued two phases earlier) in mm_loop users; kvp stays 2-deep.

constexpr int Bn  = 8;
constexpr int Sn  = 2048;
constexpr int Cn  = 512;
constexpr int Tn  = 128;
constexpr int NCn = 16;
constexpr float DKf = 0.04419417382415922f;     // 1/sqrt(512)

typedef __attribute__((ext_vector_type(8))) short bf16x8;
typedef __attribute__((ext_vector_type(4))) float f32x4;

__device__ __forceinline__ unsigned short f2bf(float f) {   // RNE
  unsigned u = __float_as_uint(f);
  u = (u + 0x7fffu + ((u >> 16) & 1u)) >> 16;
  return (unsigned short)u;
}
__device__ __forceinline__ float bf2f(unsigned short h) {
  return __uint_as_float(((unsigned)h) << 16);
}
__device__ __forceinline__ float phi_f(float u) {
  float s = u * DKf;
  return s > 0.0f ? s + 1.0f : __expf(s);       // elu(s)+1
}

// ---- stage a 128x32 bf16 tile global->LDS, swizzle kslot ^= (row>>1)&3 ------
__device__ __forceinline__ void stage128x32(const unsigned short* __restrict__ g,
                                            int ld, unsigned short* lds,
                                            int wid, int lane) {
#pragma unroll
  for (int cc = 0; cc < 2; ++cc) {
    const int row = cc * 64 + wid * 16 + (lane >> 2);
    const int ks  = (lane & 3) ^ ((row >> 1) & 3);
    const unsigned short* src = g + (size_t)row * ld + ks * 8;
    unsigned short* dst = lds + (size_t)(cc * 256 + wid * 64) * 8;  // wave-uniform
    __builtin_amdgcn_global_load_lds(
        (const __attribute__((address_space(1))) void*)src,
        (__attribute__((address_space(3))) void*)dst, 16, 0, 0);
  }
}

// ---- 128x128 out tile, 4 waves (2x2 of 64x64), 3-buffer dist-2 K loop -------
// Per iter: issue stage(kt+2) [4 loads/thread] -> vmcnt(8) waits tile kt
// (issued TWO phases ago) -> s_barrier -> ds_read+MFMA -> s_barrier.
// Buffer cur is overwritten by the stage issued at kt+1 (after the end-of-kt
// barrier, when all waves finished reading cur) -> race-free.
__device__ __forceinline__ void mm_loop(const unsigned short* __restrict__ Ag, int lda,
                                        const unsigned short* __restrict__ Bg, int ldb,
                                        int nkt,
                                        unsigned short* Al, unsigned short* Bl,
                                        f32x4 acc[4][4]) {
  const int t = threadIdx.x, wid = t >> 6, lane = t & 63;
  const int wm = wid >> 1, wn = wid & 1;
  const int fr = lane & 15, kb = lane >> 4;
  stage128x32(Ag, lda, Al, wid, lane);
  stage128x32(Bg, ldb, Bl, wid, lane);
  if (nkt > 1) {
    stage128x32(Ag + 32, lda, Al + 4096, wid, lane);
    stage128x32(Bg + 32, ldb, Bl + 4096, wid, lane);
  }
  int cur = 0;
  for (int kt = 0; kt < nkt; ++kt) {
    if (kt + 2 < nkt) {
      const int nx2 = (cur + 2 >= 3) ? cur - 1 : cur + 2;
      stage128x32(Ag + (kt + 2) * 32, lda, Al + nx2 * 4096, wid, lane);
      stage128x32(Bg + (kt + 2) * 32, ldb, Bl + nx2 * 4096, wid, lane);
      asm volatile("s_waitcnt vmcnt(8)" ::: "memory");
    } else if (kt + 1 < nkt) {
      asm volatile("s_waitcnt vmcnt(4)" ::: "memory");
    } else {
      asm volatile("s_waitcnt vmcnt(0)" ::: "memory");
    }
    __builtin_amdgcn_s_barrier();
    asm volatile("" ::: "memory");          // no ds_read hoist above barrier
    const unsigned short* Ac = Al + cur * 4096;
    const unsigned short* Bc = Bl + cur * 4096;
    bf16x8 af[4], bf[4];
#pragma unroll
    for (int m = 0; m < 4; ++m) {
      const int r = wm * 64 + m * 16 + fr;
      af[m] = *(const bf16x8*)&Ac[r * 32 + ((kb ^ ((r >> 1) & 3)) << 3)];
    }
#pragma unroll
    for (int n = 0; n < 4; ++n) {
      const int r = wn * 64 + n * 16 + fr;
      bf[n] = *(const bf16x8*)&Bc[r * 32 + ((kb ^ ((r >> 1) & 3)) << 3)];
    }
#pragma unroll
    for (int m = 0; m < 4; ++m)
#pragma unroll
      for (int n = 0; n < 4; ++n)
        acc[m][n] = __builtin_amdgcn_mfma_f32_16x16x32_bf16(af[m], bf[n], acc[m][n], 0, 0, 0);
    __builtin_amdgcn_s_barrier();           // all waves done reading cur
    asm volatile("" ::: "memory");
    cur = (cur + 1 >= 3) ? 0 : cur + 1;
  }
}

// ---------------- casts ------------------------------------------------------
__global__ __launch_bounds__(256) void k_cast_x(const float* __restrict__ x,
                                                unsigned short* __restrict__ xb) {
  const size_t i8 = ((size_t)blockIdx.x * 256 + threadIdx.x) * 8;
  float4 a = *(const float4*)&x[i8];
  float4 b = *(const float4*)&x[i8 + 4];
  uint4 o;
  o.x = (unsigned)f2bf(a.x) | ((unsigned)f2bf(a.y) << 16);
  o.y = (unsigned)f2bf(a.z) | ((unsigned)f2bf(a.w) << 16);
  o.z = (unsigned)f2bf(b.x) | ((unsigned)f2bf(b.y) << 16);
  o.w = (unsigned)f2bf(b.z) | ((unsigned)f2bf(b.w) << 16);
  *(uint4*)&xb[i8] = o;
}

__global__ __launch_bounds__(256) void k_cast_w(const float* __restrict__ Wq,
                                                const float* __restrict__ Wk,
                                                const float* __restrict__ Wv,
                                                unsigned short* __restrict__ Wb) {
  const int z = blockIdx.y;
  const float* __restrict__ src = (z == 0) ? Wq : (z == 1 ? Wk : Wv);
  const size_t i8 = ((size_t)blockIdx.x * 256 + threadIdx.x) * 8;
  float4 a = *(const float4*)&src[i8];
  float4 b = *(const float4*)&src[i8 + 4];
  uint4 o;
  o.x = (unsigned)f2bf(a.x) | ((unsigned)f2bf(a.y) << 16);
  o.y = (unsigned)f2bf(a.z) | ((unsigned)f2bf(a.w) << 16);
  o.z = (unsigned)f2bf(b.x) | ((unsigned)f2bf(b.y) << 16);
  o.w = (unsigned)f2bf(b.z) | ((unsigned)f2bf(b.w) << 16);
  *(uint4*)&Wb[(size_t)z * Cn * Cn + i8] = o;
}

// ---------------- K1: projections (bf16 MFMA, XCD-local m-slabs) -------------
__global__ __launch_bounds__(256) void k_proj(
    const unsigned short* __restrict__ xb, const unsigned short* __restrict__ Wb,
    unsigned short* __restrict__ PQ, unsigned short* __restrict__ PK,
    unsigned short* __restrict__ PKt, unsigned short* __restrict__ Vt,
    float* __restrict__ zsum)
{
  __shared__ unsigned short Al[3 * 128 * 32], Bl[3 * 128 * 32];
  __shared__ float zbuf[2][128];
  const int bid = blockIdx.x;
  const int xcd = bid & 7, idx = bid >> 3;            // idx in 0..191
  const int n = idx & 3, z = (idx >> 2) % 3, mloc = idx / 12;
  const int n0 = n * 128, m0 = (xcd * 16 + mloc) * 128;
  const int t = threadIdx.x, wid = t >> 6, lane = t & 63;
  const int wm = wid >> 1, wn = wid & 1;
  f32x4 acc[4][4];
  const f32x4 zero = {0.f, 0.f, 0.f, 0.f};
#pragma unroll
  for (int m = 0; m < 4; ++m)
#pragma unroll
    for (int nn = 0; nn < 4; ++nn) acc[m][nn] = zero;

  mm_loop(xb + (size_t)m0 * Cn, Cn,
          Wb + (size_t)z * Cn * Cn + (size_t)n0 * Cn, Cn, Cn / 32, Al, Bl, acc);

  float ps[4] = {0.f, 0.f, 0.f, 0.f};
#pragma unroll
  for (int m = 0; m < 4; ++m)
#pragma unroll
    for (int nn = 0; nn < 4; ++nn) {
      const int row0 = m0 + wm * 64 + m * 16 + ((lane >> 4) << 2);
      const int col  = n0 + wn * 64 + nn * 16 + (lane & 15);
      f32x4 v = acc[m][nn];
      if (z == 0) {
#pragma unroll
        for (int j = 0; j < 4; ++j)
          PQ[(size_t)(row0 + j) * Cn + col] = f2bf(phi_f(v[j]));
      } else if (z == 1) {
        ushort4 p;
#pragma unroll
        for (int j = 0; j < 4; ++j) {
          unsigned short u = f2bf(phi_f(v[j]));
          PK[(size_t)(row0 + j) * Cn + col] = u;
          (&p.x)[j] = u;
          ps[nn] += bf2f(u);
        }
        const int b = row0 >> 11, tq = row0 & (Sn - 1);
        *(ushort4*)&PKt[((size_t)b * Cn + col) * Sn + tq] = p;
      } else {
        ushort4 p;
#pragma unroll
        for (int j = 0; j < 4; ++j) (&p.x)[j] = f2bf(v[j]);
        const int b = row0 >> 11, tq = row0 & (Sn - 1);
        *(ushort4*)&Vt[((size_t)b * Cn + col) * Sn + tq] = p;
      }
    }

  if (z == 1) {   // block covers one (b, chunk) x cols n0..n0+127 completely
#pragma unroll
    for (int nn = 0; nn < 4; ++nn) {
      float v = ps[nn];
      v += __shfl_xor(v, 16); v += __shfl_xor(v, 32);   // reduce over kb
      if (lane < 16) zbuf[wm][wn * 64 + nn * 16 + lane] = v;
    }
    __syncthreads();
    if (t < 128) {
      const int b = m0 >> 11, ch = (m0 >> 7) & 15;
      zsum[((size_t)b * NCn + ch) * Cn + n0 + t] = zbuf[0][t] + zbuf[1][t];
    }
  }
}

// ---------------- K2a: A = tril(PQ_c PK_c^T) bf16; scale fully fused ---------
// scale[row] = rowsum(tril) + dot(PQ_row, zpre[b][ch]) + 1e-5, zpre from zsum.
__global__ __launch_bounds__(256) void k_gram(
    const unsigned short* __restrict__ PQ, const unsigned short* __restrict__ PK,
    const float* __restrict__ zsum,
    unsigned short* __restrict__ Abuf, float* __restrict__ scale)
{
  __shared__ unsigned short Al[3 * 128 * 32], Bl[3 * 128 * 32];
  __shared__ float rsmem[2][128];
  __shared__ float zpl[512];
  const int b = blockIdx.y, ch = blockIdx.x;
  const size_t base = ((size_t)b * Sn + ch * Tn) * Cn;
  f32x4 acc[4][4];
  const f32x4 zero = {0.f, 0.f, 0.f, 0.f};
#pragma unroll
  for (int m = 0; m < 4; ++m)
#pragma unroll
    for (int n = 0; n < 4; ++n) acc[m][n] = zero;

  mm_loop(PQ + base, Cn, PK + base, Cn, Cn / 32, Al, Bl, acc);

  const int t = threadIdx.x, wid = t >> 6, lane = t & 63;
  const int wm = wid >> 1, wn = wid & 1;
  float rsum[4][4];
#pragma unroll
  for (int m = 0; m < 4; ++m)
#pragma unroll
    for (int j = 0; j < 4; ++j) rsum[m][j] = 0.f;
#pragma unroll
  for (int m = 0; m < 4; ++m)
#pragma unroll
    for (int n = 0; n < 4; ++n) {
      f32x4 v = acc[m][n];
#pragma unroll
      for (int j = 0; j < 4; ++j) {
        const int row = wm * 64 + m * 16 + ((lane >> 4) << 2) + j;
        const int col = wn * 64 + n * 16 + (lane & 15);
        unsigned short u = (col <= row) ? f2bf(v[j]) : 0;
        Abuf[((size_t)(b * NCn + ch) * Tn + row) * Tn + col] = u;
        rsum[m][j] += bf2f(u);          // rowsum over the SAME rounded values
      }
    }
#pragma unroll
  for (int m = 0; m < 4; ++m)
#pragma unroll
    for (int j = 0; j < 4; ++j) {
      float r = rsum[m][j];
      r += __shfl_xor(r, 1); r += __shfl_xor(r, 2);
      r += __shfl_xor(r, 4); r += __shfl_xor(r, 8);
      if ((lane & 15) == 0)
        rsmem[wn][wm * 64 + m * 16 + ((lane >> 4) << 2) + j] = r;
    }
  // exclusive chunk-prefix of zsum -> zpl (LDS)
#pragma unroll
  for (int e = 0; e < 2; ++e) {
    const int c = t + e * 256;
    float s = 0.f;
    for (int ch2 = 0; ch2 < ch; ++ch2)
      s += zsum[((size_t)b * NCn + ch2) * Cn + c];
    zpl[c] = s;
  }
  __syncthreads();
  // per-row dot(PQ_row, zpl) + finalize scale (2 threads per row)
  const int row = t >> 1, half = (t & 1) * 256;
  const unsigned short* pq = PQ + base + (size_t)row * Cn + half;
  float dacc = 0.f;
  for (int i = 0; i < 256; i += 8) {
    uint4 q = *(const uint4*)(pq + i);
    dacc += bf2f((unsigned short)(q.x & 0xffff)) * zpl[half + i + 0]
          + bf2f((unsigned short)(q.x >> 16))    * zpl[half + i + 1]
          + bf2f((unsigned short)(q.y & 0xffff)) * zpl[half + i + 2]
          + bf2f((unsigned short)(q.y >> 16))    * zpl[half + i + 3]
          + bf2f((unsigned short)(q.z & 0xffff)) * zpl[half + i + 4]
          + bf2f((unsigned short)(q.z >> 16))    * zpl[half + i + 5]
          + bf2f((unsigned short)(q.w & 0xffff)) * zpl[half + i + 6]
          + bf2f((unsigned short)(q.w >> 16))    * zpl[half + i + 7];
  }
  dacc += __shfl_xor(dacc, 1);
  if ((t & 1) == 0)
    scale[(size_t)b * Sn + ch * Tn + row] =
        rsmem[0][row] + rsmem[1][row] + dacc + 1e-5f;
}

// ---- stage a 64x128 bf16 tile global->LDS, swizzle slot ^= row&7 ------------
__device__ __forceinline__ void stage64x128(const unsigned short* __restrict__ g,
                                            int ld, unsigned short* lds,
                                            int wid, int lane) {
#pragma unroll
  for (int i = 0; i < 4; ++i) {
    const int row = wid * 16 + i * 4 + (lane >> 4);
    const int s   = (lane & 15) ^ (row & 7);
    const unsigned short* src = g + (size_t)row * ld + s * 8;
    unsigned short* dst = lds + (size_t)(wid * 16 + i * 4) * 128;   // wave-uniform
    __builtin_amdgcn_global_load_lds(
        (const __attribute__((address_space(1))) void*)src,
        (__attribute__((address_space(3))) void*)dst, 16, 0, 0);
  }
}

// ---------------- K3a: fused KV + exclusive prefix (BK=128, counted vmcnt) ---
// 512 blocks; XCD k owns batch k. Block owns 64(c)x64(d) of M; per chunk:
// stage ch+1 (8 loads) -> vmcnt(8) -> barrier -> write prefix -> MFMA ch.
__global__ __launch_bounds__(256) void k_kvp(
    const unsigned short* __restrict__ PKt, const unsigned short* __restrict__ Vt,
    unsigned short* __restrict__ Mpre)
{
  __shared__ unsigned short Al[2 * 64 * 128], Bl[2 * 64 * 128];
  const int bid = blockIdx.x;
  const int b = bid & 7, idx = bid >> 3;
  const int d0 = (idx & 7) * 64, c0 = (idx >> 3) * 64;
  const int t = threadIdx.x, wid = t >> 6, lane = t & 63;
  const int wm = wid >> 1, wn = wid & 1;
  const int fr = lane & 15, kb = lane >> 4;
  f32x4 acc[2][2];
  const f32x4 zero = {0.f, 0.f, 0.f, 0.f};
#pragma unroll
  for (int m = 0; m < 2; ++m)
#pragma unroll
    for (int n = 0; n < 2; ++n) acc[m][n] = zero;
  const unsigned short* Ag = PKt + ((size_t)b * Cn + c0) * Sn;
  const unsigned short* Bg = Vt  + ((size_t)b * Cn + d0) * Sn;
  stage64x128(Ag, Sn, Al, wid, lane);
  stage64x128(Bg, Sn, Bl, wid, lane);
  int cur = 0;
  for (int ch = 0; ch < NCn; ++ch) {
    const int nxt = cur ^ 1;
    if (ch + 1 < NCn) {
      stage64x128(Ag + (ch + 1) * Tn, Sn, Al + nxt * 8192, wid, lane);
      stage64x128(Bg + (ch + 1) * Tn, Sn, Bl + nxt * 8192, wid, lane);
      asm volatile("s_waitcnt vmcnt(8)" ::: "memory");
    } else {
      asm volatile("s_waitcnt vmcnt(0)" ::: "memory");
    }
    __builtin_amdgcn_s_barrier();
    asm volatile("" ::: "memory");
    if (ch > 0) {   // Mpre[ch] = sum of chunks < ch (Mpre[0] never read)
#pragma unroll
      for (int m = 0; m < 2; ++m)
#pragma unroll
        for (int n = 0; n < 2; ++n) {
          const int c_row = c0 + wm * 32 + m * 16 + (kb << 2);
          const int d     = d0 + wn * 32 + n * 16 + fr;
          ushort4 p;
#pragma unroll
          for (int j = 0; j < 4; ++j) (&p.x)[j] = f2bf(acc[m][n][j]);
          *(ushort4*)&Mpre[((size_t)(b * NCn + ch) * Cn + d) * Cn + c_row] = p;
        }
    }
    const unsigned short* Ac = Al + cur * 8192;
    const unsigned short* Bc = Bl + cur * 8192;
#pragma unroll
    for (int kt = 0; kt < 4; ++kt) {
      bf16x8 af[2], bf[2];
#pragma unroll
      for (int m = 0; m < 2; ++m) {
        const int r = wm * 32 + m * 16 + fr;
        af[m] = *(const bf16x8*)&Ac[r * 128 + (((kt * 4 + kb) ^ (r & 7)) << 3)];
      }
#pragma unroll
      for (int n = 0; n < 2; ++n) {
        const int r = wn * 32 + n * 16 + fr;
        bf[n] = *(const bf16x8*)&Bc[r * 128 + (((kt * 4 + kb) ^ (r & 7)) << 3)];
      }
#pragma unroll
      for (int m = 0; m < 2; ++m)
#pragma unroll
        for (int n = 0; n < 2; ++n)
          acc[m][n] = __builtin_amdgcn_mfma_f32_16x16x32_bf16(af[m], bf[n], acc[m][n], 0, 0, 0);
    }
    __builtin_amdgcn_s_barrier();
    asm volatile("" ::: "memory");
    cur = nxt;
  }
}

// ---------------- K3b: out = (A@V_c + PQ_c@Mpre_c) / scale (single write) ----
__global__ __launch_bounds__(256) void k_avinter(
    const unsigned short* __restrict__ Abuf, const unsigned short* __restrict__ Vt,
    const unsigned short* __restrict__ PQ, const unsigned short* __restrict__ Mpre,
    const float* __restrict__ scale, float* __restrict__ out)
{
  __shared__ unsigned short Al[3 * 128 * 32], Bl[3 * 128 * 32];
  const int bid = blockIdx.x;
  const int logical = (bid & 7) * 64 + (bid >> 3);
  const int d0 = (logical & 3) * 128;
  const int ch = (logical >> 2) & 15;
  const int b  = logical >> 6;
  const int t0 = ch * Tn;
  f32x4 acc[4][4];
  const f32x4 zero = {0.f, 0.f, 0.f, 0.f};
#pragma unroll
  for (int m = 0; m < 4; ++m)
#pragma unroll
    for (int n = 0; n < 4; ++n) acc[m][n] = zero;

  // intra: A (128x128) @ V_c  (K = 128)
  mm_loop(Abuf + (size_t)(b * NCn + ch) * Tn * Tn, Tn,
          Vt + ((size_t)b * Cn + d0) * Sn + t0, Sn, Tn / 32, Al, Bl, acc);
  // inter: PQ_c @ Mpre_c  (K = 512)
  if (ch > 0)
    mm_loop(PQ + ((size_t)b * Sn + t0) * Cn, Cn,
            Mpre + ((size_t)(b * NCn + ch) * Cn + d0) * Cn, Cn, Cn / 32, Al, Bl, acc);

  const int t = threadIdx.x, wid = t >> 6, lane = t & 63;
  const int wm = wid >> 1, wn = wid & 1;
#pragma unroll
  for (int m = 0; m < 4; ++m)
#pragma unroll
    for (int n = 0; n < 4; ++n) {
      const int row0 = t0 + wm * 64 + m * 16 + ((lane >> 4) << 2);
      const int col  = d0 + wn * 64 + n * 16 + (lane & 15);
      f32x4 v = acc[m][n];
#pragma unroll
      for (int j = 0; j < 4; ++j) {
        const size_t sidx = (size_t)b * Sn + row0 + j;
        out[sidx * Cn + col] = v[j] / scale[sidx];
      }
    }
}

// ---------------- launch -----------------------------------------------------
extern "C" void kernel_launch(void* const* d_in, const int* in_sizes, int n_in,
                              void* d_out, int out_size, void* d_ws, size_t ws_size,
                              hipStream_t stream)
{
  const float* x  = (const float*)d_in[0];
  const float* Wq = (const float*)d_in[1];
  const float* Wk = (const float*)d_in[2];
  const float* Wv = (const float*)d_in[3];
  float* out = (float*)d_out;

  unsigned short* xb   = (unsigned short*)d_ws;
  unsigned short* Wb   = xb   + (size_t)Bn * Sn * Cn;          // 8.39M
  unsigned short* PQ   = Wb   + (size_t)3 * Cn * Cn;           // 0.79M
  unsigned short* PK   = PQ   + (size_t)Bn * Sn * Cn;
  unsigned short* PKt  = PK   + (size_t)Bn * Sn * Cn;
  unsigned short* Vt   = PKt  + (size_t)Bn * Sn * Cn;
  unsigned short* Abuf = Vt   + (size_t)Bn * Sn * Cn;          // 2.10M
  unsigned short* Mpre = Abuf + (size_t)Bn * NCn * Tn * Tn;    // 33.55M
  float* scale = (float*)(Mpre + (size_t)Bn * NCn * Cn * Cn);  // 16K
  float* zsum  = scale + (size_t)Bn * Sn;                      // 64K
  (void)ws_size; (void)in_sizes; (void)n_in; (void)out_size;

  hipLaunchKernelGGL(k_cast_x, dim3(4096), dim3(256), 0, stream, x, xb);
  hipLaunchKernelGGL(k_cast_w, dim3(128, 3), dim3(256), 0, stream, Wq, Wk, Wv, Wb);
  hipLaunchKernelGGL(k_proj, dim3(1536), dim3(256), 0, stream, xb, Wb, PQ, PK, PKt, Vt, zsum);
  hipLaunchKernelGGL(k_gram, dim3(NCn, Bn), dim3(256), 0, stream, PQ, PK, zsum, Abuf, scale);
  hipLaunchKernelGGL(k_kvp, dim3(512), dim3(256), 0, stream, PKt, Vt, Mpre);
  hipLaunchKernelGGL(k_avinter, dim3(512), dim3(256), 0, stream, Abuf, Vt, PQ, Mpre, scale, out);
}